// Round 4
// baseline (276.439 us; speedup 1.0000x reference)
//
#include <hip/hip_runtime.h>
#include <hip/hip_bf16.h>
#include <math.h>

// PostEncode R4: fused bf16-MFMA chain, register-budgeted.
//  - block = 1 wave, __launch_bounds__(64,2) -> 256 VGPR cap, 2 waves/SIMD
//  - Wf2/3/4 resident (96 VGPR); Wf1 streamed per tile via opaque-ptr asm
//    (prevents CSE re-residency); loads are same-address every tile -> L1-hot
//  - next-tile gathers (raw f32) prefetched during L2..L4 compute
//  - hacc/ssum kept as per-lane partials (no per-tile shuffles); single
//    c-reduction per node; pure-shfl epilogue, zero LDS
// R3 post-mortem: WRITE_SIZE 86MB/replay = ~69 VGPR spilled per wave (weight
// frags); this round eliminates the spill. Verify via WRITE_SIZE ~12MB.

#define NN 16384
#define LL 50
#define EE 64

typedef __attribute__((ext_vector_type(8))) short short8;
typedef __attribute__((ext_vector_type(4))) float f32x4;

static __device__ __forceinline__ unsigned short f2bf(float x) {
  __hip_bfloat16 h = __float2bfloat16(x);
  unsigned short u;
  __builtin_memcpy(&u, &h, 2);
  return u;
}

static __device__ __forceinline__ f32x4 ld4(const float* p) {
  return *(const f32x4*)p;
}

static __device__ __forceinline__ f32x4 relu4(f32x4 a) {
  f32x4 r;
  r[0] = fmaxf(a[0], 0.f); r[1] = fmaxf(a[1], 0.f);
  r[2] = fmaxf(a[2], 0.f); r[3] = fmaxf(a[3], 0.f);
  return r;
}

static __device__ __forceinline__ short8 pack8(f32x4 a, f32x4 b) {
  short8 r;
  r[0] = (short)f2bf(a[0]); r[1] = (short)f2bf(a[1]);
  r[2] = (short)f2bf(a[2]); r[3] = (short)f2bf(a[3]);
  r[4] = (short)f2bf(b[0]); r[5] = (short)f2bf(b[1]);
  r[6] = (short)f2bf(b[2]); r[7] = (short)f2bf(b[3]);
  return r;
}

#define MFMA(A, B, C) __builtin_amdgcn_mfma_f32_16x16x32_bf16((A), (B), (C), 0, 0, 0)

// ---------------- pack: weights -> frag-ordered bf16 (unchanged layout) ----
__global__ __launch_bounds__(256)
void pack_kernel(const float* __restrict__ W1_w, const float* __restrict__ W2_w,
                 const float* __restrict__ A1_w, const float* __restrict__ A2_w,
                 unsigned short* __restrict__ frag_ws) {
  int tid = blockIdx.x * blockDim.x + threadIdx.x;
  for (int idx = tid; idx < 2560; idx += gridDim.x * blockDim.x) {
    const float* W;
    int mt, s, lane;
    const bool isL1 = idx < 1024;
    if (isL1) {
      mt = idx >> 8; s = (idx >> 6) & 3; lane = idx & 63; W = W1_w;
    } else {
      int r = idx - 1024;
      int li = r >> 9;
      mt = (r >> 7) & 3; s = (r >> 6) & 1; lane = r & 63;
      W = (li == 0) ? W2_w : (li == 1) ? A1_w : A2_w;
    }
    const int g = lane >> 4, c = lane & 15;
#pragma unroll
    for (int j = 0; j < 8; ++j) {
      const int k = isL1 ? (32 * s + 8 * g + j)
                         : (32 * s + 16 * (j >> 2) + 4 * g + (j & 3));
      frag_ws[idx * 8 + j] = f2bf(W[k * EE + 16 * mt + c]);
    }
  }
}

// ---------------- setup: post + abase (f32) ----------------
__global__ __launch_bounds__(64)
void setup_kernel(const float* __restrict__ content_emb,
                  const int* __restrict__ pr_content,
                  const float* __restrict__ We_w, const float* __restrict__ We_b,
                  const float* __restrict__ A1_w, const float* __restrict__ A1_b,
                  float* __restrict__ post_ws, float* __restrict__ abase_ws) {
  const int n = blockIdx.x;
  const int e = threadIdx.x;
  __shared__ float ce_s[128];
  __shared__ float post_s[64];
  const float* ce = content_emb + (size_t)pr_content[n] * 128;
  ce_s[e] = ce[e];
  ce_s[64 + e] = ce[64 + e];
  __syncthreads();
  float acc = We_b[e];
#pragma unroll 8
  for (int k = 0; k < 128; ++k) acc = fmaf(ce_s[k], We_w[k * EE + e], acc);
  float po = fmaxf(acc, 0.f);
  post_s[e] = po;
  post_ws[n * EE + e] = po;
  __syncthreads();
  float ab = A1_b[e];
#pragma unroll 8
  for (int k = 0; k < 64; ++k) ab = fmaf(post_s[k], A1_w[(64 + k) * EE + e], ab);
  abase_ws[n * EE + e] = ab;
}

// ---------------- fused: MLP chain + online softmax + epilogue ----------------
__global__ __launch_bounds__(64, 2)
void fused_kernel(const float* __restrict__ u2e, const float* __restrict__ r2e,
                  const float* __restrict__ W1_b, const float* __restrict__ W2_b,
                  const float* __restrict__ A2_b,
                  const float* __restrict__ A3_w, const float* __restrict__ A3_b,
                  const float* __restrict__ Ow_w, const float* __restrict__ Ow_b,
                  const int* __restrict__ pu_history,
                  const int* __restrict__ pr_history,
                  const int* __restrict__ lengths,
                  const short8* __restrict__ pf,
                  const float* __restrict__ post_ws,
                  const float* __restrict__ abase_ws,
                  float* __restrict__ out) {
  const int lane = (int)threadIdx.x;
  const int g = lane >> 4;
  const int c = lane & 15;
  const int wave = blockIdx.x;
  const int nwaves = gridDim.x;

  // resident small-layer frags: 24 short8 = 96 VGPR
  short8 Wf2[4][2], Wf3[4][2], Wf4[4][2];
#pragma unroll
  for (int mt = 0; mt < 4; ++mt)
#pragma unroll
    for (int s = 0; s < 2; ++s) {
      Wf2[mt][s] = pf[1024 + (mt * 2 + s) * 64 + lane];
      Wf3[mt][s] = pf[1536 + (mt * 2 + s) * 64 + lane];
      Wf4[mt][s] = pf[2048 + (mt * 2 + s) * 64 + lane];
    }

  const float b3 = A3_b[0];
  const short8* pf1 = pf;  // opaque-mutated per tile to force re-load

  for (int n = wave; n < NN; n += nwaves) {
    const int len = lengths[n];
    const int ntile = (len + 15) >> 4;
    const int base = n * LL;

    // issue tile-0 gathers (t = c < 16, always a valid slot index)
    int pu = pu_history[base + c];
    int pr = pr_history[base + c];
    const float* up = u2e + (size_t)pu * EE;
    const float* rp = r2e + (size_t)pr * EE;
    f32x4 xr0 = ld4(up + 8 * g),      xr1 = ld4(up + 8 * g + 4);
    f32x4 xr2 = ld4(up + 32 + 8 * g), xr3 = ld4(up + 32 + 8 * g + 4);
    f32x4 xr4 = ld4(rp + 8 * g),      xr5 = ld4(rp + 8 * g + 4);
    f32x4 xr6 = ld4(rp + 32 + 8 * g), xr7 = ld4(rp + 32 + 8 * g + 4);

    float m = -INFINITY;
    float ssum = 0.f;          // per-lane partial
    f32x4 hacc[4];             // per-lane partial
#pragma unroll
    for (int mt = 0; mt < 4; ++mt) {
      hacc[mt][0] = 0.f; hacc[mt][1] = 0.f;
      hacc[mt][2] = 0.f; hacc[mt][3] = 0.f;
    }

    for (int lt = 0; lt < ntile; ++lt) {
      // ---- stream L1 weight frags (same addresses every tile; asm blinds
      // the compiler so they are re-loaded, not kept resident) ----
      asm volatile("" : "+s"(pf1));
      short8 Wf1[4][4];
#pragma unroll
      for (int mt = 0; mt < 4; ++mt)
#pragma unroll
        for (int s = 0; s < 4; ++s)
          Wf1[mt][s] = pf1[(mt * 4 + s) * 64 + lane];

      // ---- convert gathered rows to bf16 B-frags ----
      short8 Xf[4];
      Xf[0] = pack8(xr0, xr1);
      Xf[1] = pack8(xr2, xr3);
      Xf[2] = pack8(xr4, xr5);
      Xf[3] = pack8(xr6, xr7);

      // ---- L1: X1^T = relu(W1^T X^T + b1) ----
      f32x4 acc[4];
#pragma unroll
      for (int mt = 0; mt < 4; ++mt) acc[mt] = ld4(W1_b + 16 * mt + 4 * g);
#pragma unroll
      for (int s = 0; s < 4; ++s)
#pragma unroll
        for (int mt = 0; mt < 4; ++mt)
          acc[mt] = MFMA(Wf1[mt][s], Xf[s], acc[mt]);
#pragma unroll
      for (int mt = 0; mt < 4; ++mt) acc[mt] = relu4(acc[mt]);
      short8 Bf[2];
      Bf[0] = pack8(acc[0], acc[1]);
      Bf[1] = pack8(acc[2], acc[3]);

      // ---- prefetch next tile's gathers (hidden under L2..L4) ----
      if (lt + 1 < ntile) {
        const int t2 = ((lt + 1) << 4) + c;
        const int tc2 = (t2 < LL) ? t2 : 0;
        pu = pu_history[base + tc2];
        pr = pr_history[base + tc2];
        up = u2e + (size_t)pu * EE;
        rp = r2e + (size_t)pr * EE;
        xr0 = ld4(up + 8 * g);      xr1 = ld4(up + 8 * g + 4);
        xr2 = ld4(up + 32 + 8 * g); xr3 = ld4(up + 32 + 8 * g + 4);
        xr4 = ld4(rp + 8 * g);      xr5 = ld4(rp + 8 * g + 4);
        xr6 = ld4(rp + 32 + 8 * g); xr7 = ld4(rp + 32 + 8 * g + 4);
      }

      // ---- L2: o^T = relu(W2^T X1^T + b2) ----
      f32x4 o_[4];
#pragma unroll
      for (int mt = 0; mt < 4; ++mt) o_[mt] = ld4(W2_b + 16 * mt + 4 * g);
#pragma unroll
      for (int s = 0; s < 2; ++s)
#pragma unroll
        for (int mt = 0; mt < 4; ++mt)
          o_[mt] = MFMA(Wf2[mt][s], Bf[s], o_[mt]);
#pragma unroll
      for (int mt = 0; mt < 4; ++mt) o_[mt] = relu4(o_[mt]);
      Bf[0] = pack8(o_[0], o_[1]);
      Bf[1] = pack8(o_[2], o_[3]);

      // ---- L3: a1^T = relu(A1a^T o^T + abase[n]) ----
      f32x4 acc3[4];
#pragma unroll
      for (int mt = 0; mt < 4; ++mt)
        acc3[mt] = ld4(abase_ws + (size_t)n * EE + 16 * mt + 4 * g);
#pragma unroll
      for (int s = 0; s < 2; ++s)
#pragma unroll
        for (int mt = 0; mt < 4; ++mt)
          acc3[mt] = MFMA(Wf3[mt][s], Bf[s], acc3[mt]);
#pragma unroll
      for (int mt = 0; mt < 4; ++mt) acc3[mt] = relu4(acc3[mt]);
      Bf[0] = pack8(acc3[0], acc3[1]);
      Bf[1] = pack8(acc3[2], acc3[3]);

      // ---- L4: a2^T = relu(A2^T a1^T + b); logit = a2 . A3 + b3 ----
      f32x4 acc4[4];
#pragma unroll
      for (int mt = 0; mt < 4; ++mt) acc4[mt] = ld4(A2_b + 16 * mt + 4 * g);
#pragma unroll
      for (int s = 0; s < 2; ++s)
#pragma unroll
        for (int mt = 0; mt < 4; ++mt)
          acc4[mt] = MFMA(Wf4[mt][s], Bf[s], acc4[mt]);

      float part = 0.f;
#pragma unroll
      for (int mt = 0; mt < 4; ++mt) {
        f32x4 a3 = ld4(A3_w + 16 * mt + 4 * g);
        f32x4 r = relu4(acc4[mt]);
        part = fmaf(r[0], a3[0], part);
        part = fmaf(r[1], a3[1], part);
        part = fmaf(r[2], a3[2], part);
        part = fmaf(r[3], a3[3], part);
      }
      part += __shfl_xor(part, 16);
      part += __shfl_xor(part, 32);  // logit for this lane's row (c)

      const int t = (lt << 4) + c;
      const float lg = (t < len) ? (part + b3) : -INFINITY;

      // tile max over c -> wave-uniform within g (same across g by construction)
      float tm = lg;
      tm = fmaxf(tm, __shfl_xor(tm, 1));
      tm = fmaxf(tm, __shfl_xor(tm, 2));
      tm = fmaxf(tm, __shfl_xor(tm, 4));
      tm = fmaxf(tm, __shfl_xor(tm, 8));

      const float m_new = fmaxf(m, tm);
      const float scale = __expf(m - m_new);  // 0 on first tile
      const float w = __expf(lg - m_new);     // 0 for masked rows

      ssum = ssum * scale + w;                // per-lane partial
#pragma unroll
      for (int mt = 0; mt < 4; ++mt) {        // per-lane partial, no shuffles
        hacc[mt][0] = fmaf(w, o_[mt][0], hacc[mt][0] * scale);
        hacc[mt][1] = fmaf(w, o_[mt][1], hacc[mt][1] * scale);
        hacc[mt][2] = fmaf(w, o_[mt][2], hacc[mt][2] * scale);
        hacc[mt][3] = fmaf(w, o_[mt][3], hacc[mt][3] * scale);
      }
      m = m_new;
    }

    // ---- node-end reductions over c (butterfly; all lanes get sums) ----
    float sv = ssum;
    sv += __shfl_xor(sv, 1);
    sv += __shfl_xor(sv, 2);
    sv += __shfl_xor(sv, 4);
    sv += __shfl_xor(sv, 8);
    const float inv = 1.f / sv;

    float hred[4][4];
#pragma unroll
    for (int mt = 0; mt < 4; ++mt)
#pragma unroll
      for (int r = 0; r < 4; ++r) {
        float v = hacc[mt][r];
        v += __shfl_xor(v, 1);
        v += __shfl_xor(v, 2);
        v += __shfl_xor(v, 4);
        v += __shfl_xor(v, 8);
        hred[mt][r] = v * inv;   // hist[16mt+4g+r], valid on all lanes
      }

    // ---- epilogue: out = relu([hist;post] @ Ow + b), pure shfl ----
    const float po = post_ws[(size_t)n * EE + lane];
    float acc = Ow_b[lane];
#pragma unroll
    for (int k = 0; k < 64; ++k) {
      const int mt = k >> 4, gk = (k >> 2) & 3, r = k & 3;
      const float hk = __shfl(hred[mt][r], gk << 4);
      acc = fmaf(hk, Ow_w[k * EE + lane], acc);
    }
#pragma unroll 8
    for (int k = 0; k < 64; ++k)
      acc = fmaf(__shfl(po, k), Ow_w[(64 + k) * EE + lane], acc);
    out[(size_t)n * EE + lane] = fmaxf(acc, 0.f);
  }
}

// ---------------- R1 fallback (all-f32, no workspace) ----------------
template <int K>
__device__ __forceinline__ void mm2(const float* row0, const float* row1,
                                    const float* __restrict__ W, int e,
                                    float& acc0, float& acc1) {
  const float4* r0 = (const float4*)row0;
  const float4* r1 = (const float4*)row1;
#pragma unroll 4
  for (int k4 = 0; k4 < K / 4; ++k4) {
    float4 va = r0[k4];
    float4 vb = r1[k4];
    const float* w = W + (k4 * 4) * EE + e;
    float w0 = w[0], w1 = w[EE], w2 = w[2 * EE], w3 = w[3 * EE];
    acc0 = fmaf(va.x, w0, acc0);  acc1 = fmaf(vb.x, w0, acc1);
    acc0 = fmaf(va.y, w1, acc0);  acc1 = fmaf(vb.y, w1, acc1);
    acc0 = fmaf(va.z, w2, acc0);  acc1 = fmaf(vb.z, w2, acc1);
    acc0 = fmaf(va.w, w3, acc0);  acc1 = fmaf(vb.w, w3, acc1);
  }
}

__global__ __launch_bounds__(256, 4)
void postenc_kernel(
    const float* __restrict__ u2e, const float* __restrict__ r2e,
    const float* __restrict__ content_emb,
    const float* __restrict__ We_w, const float* __restrict__ We_b,
    const float* __restrict__ W1_w, const float* __restrict__ W1_b,
    const float* __restrict__ W2_w, const float* __restrict__ W2_b,
    const float* __restrict__ A1_w, const float* __restrict__ A1_b,
    const float* __restrict__ A2_w, const float* __restrict__ A2_b,
    const float* __restrict__ A3_w, const float* __restrict__ A3_b,
    const float* __restrict__ Ow_w, const float* __restrict__ Ow_b,
    const int* __restrict__ pu_history, const int* __restrict__ pr_history,
    const int* __restrict__ lengths, const int* __restrict__ pr_content,
    float* __restrict__ out) {
  const int n = blockIdx.x;
  const int tid = (int)threadIdx.x;
  const int e = tid & 63;
  const int g = tid >> 6;

  __shared__ float post_s[EE];
  __shared__ float abase_s[EE];
  __shared__ float in_s[8][128];
  __shared__ float x_s[8][EE];
  __shared__ float a_s[8][EE];
  __shared__ float o_s[56][EE];
  __shared__ float logit_s[EE];
  __shared__ float att_s[EE];
  __shared__ float red_s[4][EE];

  const int len = lengths[n];
  float p = 0.f;

  if (g == 0) {
    const float* ce = content_emb + (size_t)pr_content[n] * 128;
    float acc = We_b[e];
#pragma unroll 4
    for (int k = 0; k < 128; ++k) acc = fmaf(ce[k], We_w[k * EE + e], acc);
    p = fmaxf(acc, 0.f);
    post_s[e] = p;
    float ab = A1_b[e];
#pragma unroll
    for (int k = 0; k < 64; ++k) {
      float pk = __shfl(p, k);
      ab = fmaf(pk, A1_w[(64 + k) * EE + e], ab);
    }
    abase_s[e] = ab;
    logit_s[e] = -INFINITY;
  }
  __syncthreads();

  for (int lb = 0; lb < 56; lb += 8) {
    const int l0 = lb + g;
    const int l1 = l0 + 4;
    const bool v0 = l0 < LL;
    const bool v1 = l1 < LL;

    int pu0 = 0, pr0 = 0, pu1 = 0, pr1 = 0;
    if (v0) { pu0 = pu_history[n * LL + l0]; pr0 = pr_history[n * LL + l0]; }
    if (v1) { pu1 = pu_history[n * LL + l1]; pr1 = pr_history[n * LL + l1]; }
    in_s[g][e]          = v0 ? u2e[(size_t)pu0 * EE + e] : 0.f;
    in_s[g][64 + e]     = v0 ? r2e[pr0 * EE + e]         : 0.f;
    in_s[g + 4][e]      = v1 ? u2e[(size_t)pu1 * EE + e] : 0.f;
    in_s[g + 4][64 + e] = v1 ? r2e[pr1 * EE + e]         : 0.f;
    __syncthreads();

    float acc0 = W1_b[e], acc1 = acc0;
    mm2<128>(in_s[g], in_s[g + 4], W1_w, e, acc0, acc1);
    x_s[g][e]     = fmaxf(acc0, 0.f);
    x_s[g + 4][e] = fmaxf(acc1, 0.f);
    __syncthreads();

    acc0 = W2_b[e]; acc1 = acc0;
    mm2<64>(x_s[g], x_s[g + 4], W2_w, e, acc0, acc1);
    float o0 = fmaxf(acc0, 0.f);
    float o1 = fmaxf(acc1, 0.f);
    if (v0) o_s[l0][e] = o0;
    if (v1) o_s[l1][e] = o1;
    x_s[g][e]     = o0;
    x_s[g + 4][e] = o1;
    __syncthreads();

    acc0 = abase_s[e]; acc1 = acc0;
    mm2<64>(x_s[g], x_s[g + 4], A1_w, e, acc0, acc1);
    a_s[g][e]     = fmaxf(acc0, 0.f);
    a_s[g + 4][e] = fmaxf(acc1, 0.f);
    __syncthreads();

    acc0 = A2_b[e]; acc1 = acc0;
    mm2<64>(a_s[g], a_s[g + 4], A2_w, e, acc0, acc1);
    float w3 = A3_w[e];
    float p0 = fmaxf(acc0, 0.f) * w3;
    float p1 = fmaxf(acc1, 0.f) * w3;
#pragma unroll
    for (int off = 32; off > 0; off >>= 1) {
      p0 += __shfl_xor(p0, off);
      p1 += __shfl_xor(p1, off);
    }
    if (e == 0) {
      float b3 = A3_b[0];
      if (l0 < len) logit_s[l0] = p0 + b3;
      if (l1 < len) logit_s[l1] = p1 + b3;
    }
    __syncthreads();
  }

  if (g == 0) {
    float lg = logit_s[e];
    float m = lg;
#pragma unroll
    for (int off = 32; off > 0; off >>= 1) m = fmaxf(m, __shfl_xor(m, off));
    float pe = __expf(lg - m);
    float sm = pe;
#pragma unroll
    for (int off = 32; off > 0; off >>= 1) sm += __shfl_xor(sm, off);
    att_s[e] = pe / sm;
  }
  __syncthreads();

  {
    const int l_lo = 13 * g;
    const int l_hi = (13 * g + 13 < LL) ? 13 * g + 13 : LL;
    float h = 0.f;
    for (int l = l_lo; l < l_hi; ++l) h = fmaf(att_s[l], o_s[l][e], h);
    red_s[g][e] = h;
  }
  __syncthreads();

  if (g == 0) {
    float h = red_s[0][e] + red_s[1][e] + red_s[2][e] + red_s[3][e];
    float acc = Ow_b[e];
#pragma unroll
    for (int k = 0; k < 64; ++k) {
      float hk = __shfl(h, k);
      acc = fmaf(hk, Ow_w[k * EE + e], acc);
    }
#pragma unroll
    for (int k = 0; k < 64; ++k) {
      float pk = __shfl(p, k);
      acc = fmaf(pk, Ow_w[(64 + k) * EE + e], acc);
    }
    out[(size_t)n * EE + e] = fmaxf(acc, 0.f);
  }
}

// ---------------- launcher ----------------
extern "C" void kernel_launch(void* const* d_in, const int* in_sizes, int n_in,
                              void* d_out, int out_size, void* d_ws, size_t ws_size,
                              hipStream_t stream) {
  const float* u2e         = (const float*)d_in[0];
  const float* r2e         = (const float*)d_in[1];
  const float* content_emb = (const float*)d_in[2];
  const float* We_w = (const float*)d_in[3];
  const float* We_b = (const float*)d_in[4];
  const float* W1_w = (const float*)d_in[5];
  const float* W1_b = (const float*)d_in[6];
  const float* W2_w = (const float*)d_in[7];
  const float* W2_b = (const float*)d_in[8];
  const float* A1_w = (const float*)d_in[9];
  const float* A1_b = (const float*)d_in[10];
  const float* A2_w = (const float*)d_in[11];
  const float* A2_b = (const float*)d_in[12];
  const float* A3_w = (const float*)d_in[13];
  const float* A3_b = (const float*)d_in[14];
  const float* Ow_w = (const float*)d_in[15];
  const float* Ow_b = (const float*)d_in[16];
  // d_in[17] = nodes (unused)
  const int* pu_history = (const int*)d_in[18];
  const int* pr_history = (const int*)d_in[19];
  const int* lengths    = (const int*)d_in[20];
  const int* pr_content = (const int*)d_in[21];
  float* out = (float*)d_out;

  // workspace layout (bytes)
  const size_t FR_OFF = 0;                         // 2560 short8 = 40960 B
  const size_t PO_OFF = 65536;                     // post f32 [N*64]
  const size_t AB_OFF = PO_OFF + (size_t)NN * EE * 4;
  const size_t NEED   = AB_OFF + (size_t)NN * EE * 4;   // ~8.45 MB

  if (ws_size < NEED) {
    postenc_kernel<<<NN, 256, 0, stream>>>(
        u2e, r2e, content_emb, We_w, We_b, W1_w, W1_b, W2_w, W2_b,
        A1_w, A1_b, A2_w, A2_b, A3_w, A3_b, Ow_w, Ow_b,
        pu_history, pr_history, lengths, pr_content, out);
    return;
  }

  char* w = (char*)d_ws;
  unsigned short* frag_ws = (unsigned short*)(w + FR_OFF);
  float* post_ws  = (float*)(w + PO_OFF);
  float* abase_ws = (float*)(w + AB_OFF);

  pack_kernel<<<4, 256, 0, stream>>>(W1_w, W2_w, A1_w, A2_w, frag_ws);
  setup_kernel<<<NN, 64, 0, stream>>>(content_emb, pr_content, We_w, We_b,
                                      A1_w, A1_b, post_ws, abase_ws);
  fused_kernel<<<4096, 64, 0, stream>>>(
      u2e, r2e, W1_b, W2_b, A2_b, A3_w, A3_b, Ow_w, Ow_b,
      pu_history, pr_history, lengths, (const short8*)frag_ws,
      post_ws, abase_ws, out);
}

// Round 5
// 261.611 us; speedup vs baseline: 1.0567x; 1.0567x over previous
//
#include <hip/hip_runtime.h>
#include <hip/hip_bf16.h>
#include <math.h>

// PostEncode R5: fused bf16-MFMA chain; weights live in LDS, not VGPRs.
// R4 post-mortem: compiler allocated 128 VGPRs and spilled the resident
// weight frags to scratch (WRITE_SIZE 67MB/launch, re-read every tile).
// Fix: stage all packed frags (40KB) + biases (1KB) in LDS per block; read
// per tile via ds_read_b128 with an asm-blinded zero offset so the reads
// CANNOT be hoisted into resident registers. Per-lane state ~140 VGPR
// under __launch_bounds__(256,3) cap (170) -> no spill, 12 waves/CU.
//  - per-lane hacc/ssum partials, single c-reduction per node (from R4)
//  - next-tile gathers prefetched during L2..L4 compute (from R4)
//  - pure-shfl epilogue

#define NN 16384
#define LL 50
#define EE 64

typedef __attribute__((ext_vector_type(8))) short short8;
typedef __attribute__((ext_vector_type(4))) float f32x4;

static __device__ __forceinline__ unsigned short f2bf(float x) {
  __hip_bfloat16 h = __float2bfloat16(x);
  unsigned short u;
  __builtin_memcpy(&u, &h, 2);
  return u;
}

static __device__ __forceinline__ f32x4 ld4(const float* p) {
  return *(const f32x4*)p;
}

static __device__ __forceinline__ f32x4 relu4(f32x4 a) {
  f32x4 r;
  r[0] = fmaxf(a[0], 0.f); r[1] = fmaxf(a[1], 0.f);
  r[2] = fmaxf(a[2], 0.f); r[3] = fmaxf(a[3], 0.f);
  return r;
}

static __device__ __forceinline__ short8 pack8(f32x4 a, f32x4 b) {
  short8 r;
  r[0] = (short)f2bf(a[0]); r[1] = (short)f2bf(a[1]);
  r[2] = (short)f2bf(a[2]); r[3] = (short)f2bf(a[3]);
  r[4] = (short)f2bf(b[0]); r[5] = (short)f2bf(b[1]);
  r[6] = (short)f2bf(b[2]); r[7] = (short)f2bf(b[3]);
  return r;
}

#define MFMA(A, B, C) __builtin_amdgcn_mfma_f32_16x16x32_bf16((A), (B), (C), 0, 0, 0)

// ---------------- pack: weights -> frag-ordered bf16 ----------------
// short8 index layout: [0,1024) L1 (mt*4+s)*64+lane ; [1024,1536) L2 ;
// [1536,2048) L3 (A1 rows 0..63) ; [2048,2560) L4. Element j of lane
// (g=lane>>4, c=lane&15):  L1: k=32s+8g+j ; others: k=32s+16(j>>2)+4g+(j&3).
__global__ __launch_bounds__(256)
void pack_kernel(const float* __restrict__ W1_w, const float* __restrict__ W2_w,
                 const float* __restrict__ A1_w, const float* __restrict__ A2_w,
                 unsigned short* __restrict__ frag_ws) {
  int tid = blockIdx.x * blockDim.x + threadIdx.x;
  for (int idx = tid; idx < 2560; idx += gridDim.x * blockDim.x) {
    const float* W;
    int mt, s, lane;
    const bool isL1 = idx < 1024;
    if (isL1) {
      mt = idx >> 8; s = (idx >> 6) & 3; lane = idx & 63; W = W1_w;
    } else {
      int r = idx - 1024;
      int li = r >> 9;
      mt = (r >> 7) & 3; s = (r >> 6) & 1; lane = r & 63;
      W = (li == 0) ? W2_w : (li == 1) ? A1_w : A2_w;
    }
    const int g = lane >> 4, c = lane & 15;
#pragma unroll
    for (int j = 0; j < 8; ++j) {
      const int k = isL1 ? (32 * s + 8 * g + j)
                         : (32 * s + 16 * (j >> 2) + 4 * g + (j & 3));
      frag_ws[idx * 8 + j] = f2bf(W[k * EE + 16 * mt + c]);
    }
  }
}

// ---------------- setup: post + abase (f32) ----------------
__global__ __launch_bounds__(64)
void setup_kernel(const float* __restrict__ content_emb,
                  const int* __restrict__ pr_content,
                  const float* __restrict__ We_w, const float* __restrict__ We_b,
                  const float* __restrict__ A1_w, const float* __restrict__ A1_b,
                  float* __restrict__ post_ws, float* __restrict__ abase_ws) {
  const int n = blockIdx.x;
  const int e = threadIdx.x;
  __shared__ float ce_s[128];
  __shared__ float post_s[64];
  const float* ce = content_emb + (size_t)pr_content[n] * 128;
  ce_s[e] = ce[e];
  ce_s[64 + e] = ce[64 + e];
  __syncthreads();
  float acc = We_b[e];
#pragma unroll 8
  for (int k = 0; k < 128; ++k) acc = fmaf(ce_s[k], We_w[k * EE + e], acc);
  float po = fmaxf(acc, 0.f);
  post_s[e] = po;
  post_ws[n * EE + e] = po;
  __syncthreads();
  float ab = A1_b[e];
#pragma unroll 8
  for (int k = 0; k < 64; ++k) ab = fmaf(post_s[k], A1_w[(64 + k) * EE + e], ab);
  abase_ws[n * EE + e] = ab;
}

// ---------------- fused: LDS-weight MLP chain + online softmax ----------------
__global__ __launch_bounds__(256, 3)
void fused_kernel(const float* __restrict__ u2e, const float* __restrict__ r2e,
                  const float* __restrict__ W1_b, const float* __restrict__ W2_b,
                  const float* __restrict__ A2_b,
                  const float* __restrict__ A3_w, const float* __restrict__ A3_b,
                  const float* __restrict__ Ow_w, const float* __restrict__ Ow_b,
                  const int* __restrict__ pu_history,
                  const int* __restrict__ pr_history,
                  const int* __restrict__ lengths,
                  const short8* __restrict__ pf,
                  const float* __restrict__ post_ws,
                  const float* __restrict__ abase_ws,
                  float* __restrict__ out) {
  const int lane = (int)(threadIdx.x & 63u);
  const int g = lane >> 4;
  const int c = lane & 15;
  const int wave = blockIdx.x * 4 + (int)(threadIdx.x >> 6);
  const int nwaves = gridDim.x * 4;

  // ---- stage packed frags (40KB) + biases (1KB) into LDS ----
  __shared__ short8 wf_s[2560 + 64];
  for (int i = (int)threadIdx.x; i < 2560; i += 256) wf_s[i] = pf[i];
  {
    float* bias_s = (float*)(wf_s + 2560);
    const int t = (int)threadIdx.x;
    if (t < 64) {
      bias_s[t]       = W1_b[t];
      bias_s[64 + t]  = W2_b[t];
      bias_s[128 + t] = A2_b[t];
      bias_s[192 + t] = A3_w[t];
    }
  }
  __syncthreads();

  const float b3 = A3_b[0];

  for (int n = wave; n < NN; n += nwaves) {
    const int len = lengths[n];
    const int ntile = (len + 15) >> 4;
    const int base = n * LL;

    // per-node abase (f32x4 x4 in regs)
    f32x4 ab[4];
#pragma unroll
    for (int mt = 0; mt < 4; ++mt)
      ab[mt] = ld4(abase_ws + (size_t)n * EE + 16 * mt + 4 * g);

    // issue tile-0 gathers (t = c < 16 is always a populated slot)
    int pu = pu_history[base + c];
    int pr = pr_history[base + c];
    const float* up = u2e + (size_t)pu * EE;
    const float* rp = r2e + (size_t)pr * EE;
    f32x4 xr0 = ld4(up + 8 * g),      xr1 = ld4(up + 8 * g + 4);
    f32x4 xr2 = ld4(up + 32 + 8 * g), xr3 = ld4(up + 32 + 8 * g + 4);
    f32x4 xr4 = ld4(rp + 8 * g),      xr5 = ld4(rp + 8 * g + 4);
    f32x4 xr6 = ld4(rp + 32 + 8 * g), xr7 = ld4(rp + 32 + 8 * g + 4);

    float m = -INFINITY;
    float ssum = 0.f;          // per-lane partial
    f32x4 hacc[4];             // per-lane partial
#pragma unroll
    for (int mt = 0; mt < 4; ++mt) {
      hacc[mt][0] = 0.f; hacc[mt][1] = 0.f;
      hacc[mt][2] = 0.f; hacc[mt][3] = 0.f;
    }

    int wofs = 0;  // blinded each tile: LDS reads cannot be hoisted/CSEd
    for (int lt = 0; lt < ntile; ++lt) {
      asm volatile("" : "+v"(wofs));
      const short8* wp = wf_s + wofs;
      const float* bp = (const float*)(wf_s + 2560) + wofs;

      // ---- convert gathered rows to bf16 B-frags ----
      short8 Xf[4];
      Xf[0] = pack8(xr0, xr1);
      Xf[1] = pack8(xr2, xr3);
      Xf[2] = pack8(xr4, xr5);
      Xf[3] = pack8(xr6, xr7);

      // ---- L1: X1^T = relu(W1^T X^T + b1) ----
      f32x4 acc[4];
#pragma unroll
      for (int mt = 0; mt < 4; ++mt) acc[mt] = ld4(bp + 16 * mt + 4 * g);
#pragma unroll
      for (int s = 0; s < 4; ++s)
#pragma unroll
        for (int mt = 0; mt < 4; ++mt)
          acc[mt] = MFMA(wp[(mt * 4 + s) * 64 + lane], Xf[s], acc[mt]);
#pragma unroll
      for (int mt = 0; mt < 4; ++mt) acc[mt] = relu4(acc[mt]);
      short8 Bf[2];
      Bf[0] = pack8(acc[0], acc[1]);
      Bf[1] = pack8(acc[2], acc[3]);

      // ---- prefetch next tile's gathers (hidden under L2..L4) ----
      if (lt + 1 < ntile) {
        const int t2 = ((lt + 1) << 4) + c;
        const int tc2 = (t2 < LL) ? t2 : 0;
        pu = pu_history[base + tc2];
        pr = pr_history[base + tc2];
        up = u2e + (size_t)pu * EE;
        rp = r2e + (size_t)pr * EE;
        xr0 = ld4(up + 8 * g);      xr1 = ld4(up + 8 * g + 4);
        xr2 = ld4(up + 32 + 8 * g); xr3 = ld4(up + 32 + 8 * g + 4);
        xr4 = ld4(rp + 8 * g);      xr5 = ld4(rp + 8 * g + 4);
        xr6 = ld4(rp + 32 + 8 * g); xr7 = ld4(rp + 32 + 8 * g + 4);
      }

      // ---- L2: o^T = relu(W2^T X1^T + b2) ----
      f32x4 o_[4];
#pragma unroll
      for (int mt = 0; mt < 4; ++mt) o_[mt] = ld4(bp + 64 + 16 * mt + 4 * g);
#pragma unroll
      for (int s = 0; s < 2; ++s)
#pragma unroll
        for (int mt = 0; mt < 4; ++mt)
          o_[mt] = MFMA(wp[1024 + (mt * 2 + s) * 64 + lane], Bf[s], o_[mt]);
#pragma unroll
      for (int mt = 0; mt < 4; ++mt) o_[mt] = relu4(o_[mt]);
      Bf[0] = pack8(o_[0], o_[1]);
      Bf[1] = pack8(o_[2], o_[3]);

      // ---- L3: a1^T = relu(A1a^T o^T + abase[n]) ----
      f32x4 acc3[4];
#pragma unroll
      for (int mt = 0; mt < 4; ++mt) acc3[mt] = ab[mt];
#pragma unroll
      for (int s = 0; s < 2; ++s)
#pragma unroll
        for (int mt = 0; mt < 4; ++mt)
          acc3[mt] = MFMA(wp[1536 + (mt * 2 + s) * 64 + lane], Bf[s], acc3[mt]);
#pragma unroll
      for (int mt = 0; mt < 4; ++mt) acc3[mt] = relu4(acc3[mt]);
      Bf[0] = pack8(acc3[0], acc3[1]);
      Bf[1] = pack8(acc3[2], acc3[3]);

      // ---- L4: a2^T = relu(A2^T a1^T + b); logit = a2 . A3 + b3 ----
      f32x4 acc4[4];
#pragma unroll
      for (int mt = 0; mt < 4; ++mt) acc4[mt] = ld4(bp + 128 + 16 * mt + 4 * g);
#pragma unroll
      for (int s = 0; s < 2; ++s)
#pragma unroll
        for (int mt = 0; mt < 4; ++mt)
          acc4[mt] = MFMA(wp[2048 + (mt * 2 + s) * 64 + lane], Bf[s], acc4[mt]);

      float part = 0.f;
#pragma unroll
      for (int mt = 0; mt < 4; ++mt) {
        f32x4 a3 = ld4(bp + 192 + 16 * mt + 4 * g);
        f32x4 r = relu4(acc4[mt]);
        part = fmaf(r[0], a3[0], part);
        part = fmaf(r[1], a3[1], part);
        part = fmaf(r[2], a3[2], part);
        part = fmaf(r[3], a3[3], part);
      }
      part += __shfl_xor(part, 16);
      part += __shfl_xor(part, 32);  // logit for this lane's row (c)

      const int t = (lt << 4) + c;
      const float lg = (t < len) ? (part + b3) : -INFINITY;

      // tile max over c -> uniform across the wave
      float tm = lg;
      tm = fmaxf(tm, __shfl_xor(tm, 1));
      tm = fmaxf(tm, __shfl_xor(tm, 2));
      tm = fmaxf(tm, __shfl_xor(tm, 4));
      tm = fmaxf(tm, __shfl_xor(tm, 8));

      const float m_new = fmaxf(m, tm);
      const float scale = __expf(m - m_new);  // 0 on first tile
      const float w = __expf(lg - m_new);     // 0 for masked rows

      ssum = ssum * scale + w;                // per-lane partial
#pragma unroll
      for (int mt = 0; mt < 4; ++mt) {        // per-lane partials, no shuffles
        hacc[mt][0] = fmaf(w, o_[mt][0], hacc[mt][0] * scale);
        hacc[mt][1] = fmaf(w, o_[mt][1], hacc[mt][1] * scale);
        hacc[mt][2] = fmaf(w, o_[mt][2], hacc[mt][2] * scale);
        hacc[mt][3] = fmaf(w, o_[mt][3], hacc[mt][3] * scale);
      }
      m = m_new;
    }

    // ---- node-end reductions over c (butterfly; all lanes get sums) ----
    float sv = ssum;
    sv += __shfl_xor(sv, 1);
    sv += __shfl_xor(sv, 2);
    sv += __shfl_xor(sv, 4);
    sv += __shfl_xor(sv, 8);
    const float inv = 1.f / sv;

    float hred[4][4];
#pragma unroll
    for (int mt = 0; mt < 4; ++mt)
#pragma unroll
      for (int r = 0; r < 4; ++r) {
        float v = hacc[mt][r];
        v += __shfl_xor(v, 1);
        v += __shfl_xor(v, 2);
        v += __shfl_xor(v, 4);
        v += __shfl_xor(v, 8);
        hred[mt][r] = v * inv;   // hist[16mt+4g+r], valid on all lanes
      }

    // ---- epilogue: out = relu([hist;post] @ Ow + b), pure shfl ----
    const float po = post_ws[(size_t)n * EE + lane];
    float acc = Ow_b[lane];
#pragma unroll
    for (int k = 0; k < 64; ++k) {
      const int mt = k >> 4, gk = (k >> 2) & 3, r = k & 3;
      const float hk = __shfl(hred[mt][r], gk << 4);
      acc = fmaf(hk, Ow_w[k * EE + lane], acc);
    }
#pragma unroll 8
    for (int k = 0; k < 64; ++k)
      acc = fmaf(__shfl(po, k), Ow_w[(64 + k) * EE + lane], acc);
    out[(size_t)n * EE + lane] = fmaxf(acc, 0.f);
  }
}

// ---------------- R1 fallback (all-f32, no workspace) ----------------
template <int K>
__device__ __forceinline__ void mm2(const float* row0, const float* row1,
                                    const float* __restrict__ W, int e,
                                    float& acc0, float& acc1) {
  const float4* r0 = (const float4*)row0;
  const float4* r1 = (const float4*)row1;
#pragma unroll 4
  for (int k4 = 0; k4 < K / 4; ++k4) {
    float4 va = r0[k4];
    float4 vb = r1[k4];
    const float* w = W + (k4 * 4) * EE + e;
    float w0 = w[0], w1 = w[EE], w2 = w[2 * EE], w3 = w[3 * EE];
    acc0 = fmaf(va.x, w0, acc0);  acc1 = fmaf(vb.x, w0, acc1);
    acc0 = fmaf(va.y, w1, acc0);  acc1 = fmaf(vb.y, w1, acc1);
    acc0 = fmaf(va.z, w2, acc0);  acc1 = fmaf(vb.z, w2, acc1);
    acc0 = fmaf(va.w, w3, acc0);  acc1 = fmaf(vb.w, w3, acc1);
  }
}

__global__ __launch_bounds__(256, 4)
void postenc_kernel(
    const float* __restrict__ u2e, const float* __restrict__ r2e,
    const float* __restrict__ content_emb,
    const float* __restrict__ We_w, const float* __restrict__ We_b,
    const float* __restrict__ W1_w, const float* __restrict__ W1_b,
    const float* __restrict__ W2_w, const float* __restrict__ W2_b,
    const float* __restrict__ A1_w, const float* __restrict__ A1_b,
    const float* __restrict__ A2_w, const float* __restrict__ A2_b,
    const float* __restrict__ A3_w, const float* __restrict__ A3_b,
    const float* __restrict__ Ow_w, const float* __restrict__ Ow_b,
    const int* __restrict__ pu_history, const int* __restrict__ pr_history,
    const int* __restrict__ lengths, const int* __restrict__ pr_content,
    float* __restrict__ out) {
  const int n = blockIdx.x;
  const int tid = (int)threadIdx.x;
  const int e = tid & 63;
  const int g = tid >> 6;

  __shared__ float post_s[EE];
  __shared__ float abase_s[EE];
  __shared__ float in_s[8][128];
  __shared__ float x_s[8][EE];
  __shared__ float a_s[8][EE];
  __shared__ float o_s[56][EE];
  __shared__ float logit_s[EE];
  __shared__ float att_s[EE];
  __shared__ float red_s[4][EE];

  const int len = lengths[n];
  float p = 0.f;

  if (g == 0) {
    const float* ce = content_emb + (size_t)pr_content[n] * 128;
    float acc = We_b[e];
#pragma unroll 4
    for (int k = 0; k < 128; ++k) acc = fmaf(ce[k], We_w[k * EE + e], acc);
    p = fmaxf(acc, 0.f);
    post_s[e] = p;
    float ab = A1_b[e];
#pragma unroll
    for (int k = 0; k < 64; ++k) {
      float pk = __shfl(p, k);
      ab = fmaf(pk, A1_w[(64 + k) * EE + e], ab);
    }
    abase_s[e] = ab;
    logit_s[e] = -INFINITY;
  }
  __syncthreads();

  for (int lb = 0; lb < 56; lb += 8) {
    const int l0 = lb + g;
    const int l1 = l0 + 4;
    const bool v0 = l0 < LL;
    const bool v1 = l1 < LL;

    int pu0 = 0, pr0 = 0, pu1 = 0, pr1 = 0;
    if (v0) { pu0 = pu_history[n * LL + l0]; pr0 = pr_history[n * LL + l0]; }
    if (v1) { pu1 = pu_history[n * LL + l1]; pr1 = pr_history[n * LL + l1]; }
    in_s[g][e]          = v0 ? u2e[(size_t)pu0 * EE + e] : 0.f;
    in_s[g][64 + e]     = v0 ? r2e[pr0 * EE + e]         : 0.f;
    in_s[g + 4][e]      = v1 ? u2e[(size_t)pu1 * EE + e] : 0.f;
    in_s[g + 4][64 + e] = v1 ? r2e[pr1 * EE + e]         : 0.f;
    __syncthreads();

    float acc0 = W1_b[e], acc1 = acc0;
    mm2<128>(in_s[g], in_s[g + 4], W1_w, e, acc0, acc1);
    x_s[g][e]     = fmaxf(acc0, 0.f);
    x_s[g + 4][e] = fmaxf(acc1, 0.f);
    __syncthreads();

    acc0 = W2_b[e]; acc1 = acc0;
    mm2<64>(x_s[g], x_s[g + 4], W2_w, e, acc0, acc1);
    float o0 = fmaxf(acc0, 0.f);
    float o1 = fmaxf(acc1, 0.f);
    if (v0) o_s[l0][e] = o0;
    if (v1) o_s[l1][e] = o1;
    x_s[g][e]     = o0;
    x_s[g + 4][e] = o1;
    __syncthreads();

    acc0 = abase_s[e]; acc1 = acc0;
    mm2<64>(x_s[g], x_s[g + 4], A1_w, e, acc0, acc1);
    a_s[g][e]     = fmaxf(acc0, 0.f);
    a_s[g + 4][e] = fmaxf(acc1, 0.f);
    __syncthreads();

    acc0 = A2_b[e]; acc1 = acc0;
    mm2<64>(a_s[g], a_s[g + 4], A2_w, e, acc0, acc1);
    float w3 = A3_w[e];
    float p0 = fmaxf(acc0, 0.f) * w3;
    float p1 = fmaxf(acc1, 0.f) * w3;
#pragma unroll
    for (int off = 32; off > 0; off >>= 1) {
      p0 += __shfl_xor(p0, off);
      p1 += __shfl_xor(p1, off);
    }
    if (e == 0) {
      float b3 = A3_b[0];
      if (l0 < len) logit_s[l0] = p0 + b3;
      if (l1 < len) logit_s[l1] = p1 + b3;
    }
    __syncthreads();
  }

  if (g == 0) {
    float lg = logit_s[e];
    float m = lg;
#pragma unroll
    for (int off = 32; off > 0; off >>= 1) m = fmaxf(m, __shfl_xor(m, off));
    float pe = __expf(lg - m);
    float sm = pe;
#pragma unroll
    for (int off = 32; off > 0; off >>= 1) sm += __shfl_xor(sm, off);
    att_s[e] = pe / sm;
  }
  __syncthreads();

  {
    const int l_lo = 13 * g;
    const int l_hi = (13 * g + 13 < LL) ? 13 * g + 13 : LL;
    float h = 0.f;
    for (int l = l_lo; l < l_hi; ++l) h = fmaf(att_s[l], o_s[l][e], h);
    red_s[g][e] = h;
  }
  __syncthreads();

  if (g == 0) {
    float h = red_s[0][e] + red_s[1][e] + red_s[2][e] + red_s[3][e];
    float acc = Ow_b[e];
#pragma unroll
    for (int k = 0; k < 64; ++k) {
      float hk = __shfl(h, k);
      acc = fmaf(hk, Ow_w[k * EE + e], acc);
    }
#pragma unroll
    for (int k = 0; k < 64; ++k) {
      float pk = __shfl(p, k);
      acc = fmaf(pk, Ow_w[(64 + k) * EE + e], acc);
    }
    out[(size_t)n * EE + e] = fmaxf(acc, 0.f);
  }
}

// ---------------- launcher ----------------
extern "C" void kernel_launch(void* const* d_in, const int* in_sizes, int n_in,
                              void* d_out, int out_size, void* d_ws, size_t ws_size,
                              hipStream_t stream) {
  const float* u2e         = (const float*)d_in[0];
  const float* r2e         = (const float*)d_in[1];
  const float* content_emb = (const float*)d_in[2];
  const float* We_w = (const float*)d_in[3];
  const float* We_b = (const float*)d_in[4];
  const float* W1_w = (const float*)d_in[5];
  const float* W1_b = (const float*)d_in[6];
  const float* W2_w = (const float*)d_in[7];
  const float* W2_b = (const float*)d_in[8];
  const float* A1_w = (const float*)d_in[9];
  const float* A1_b = (const float*)d_in[10];
  const float* A2_w = (const float*)d_in[11];
  const float* A2_b = (const float*)d_in[12];
  const float* A3_w = (const float*)d_in[13];
  const float* A3_b = (const float*)d_in[14];
  const float* Ow_w = (const float*)d_in[15];
  const float* Ow_b = (const float*)d_in[16];
  // d_in[17] = nodes (unused)
  const int* pu_history = (const int*)d_in[18];
  const int* pr_history = (const int*)d_in[19];
  const int* lengths    = (const int*)d_in[20];
  const int* pr_content = (const int*)d_in[21];
  float* out = (float*)d_out;

  // workspace layout (bytes)
  const size_t FR_OFF = 0;                         // 2560 short8 = 40960 B
  const size_t PO_OFF = 65536;                     // post f32 [N*64]
  const size_t AB_OFF = PO_OFF + (size_t)NN * EE * 4;
  const size_t NEED   = AB_OFF + (size_t)NN * EE * 4;   // ~8.45 MB

  if (ws_size < NEED) {
    postenc_kernel<<<NN, 256, 0, stream>>>(
        u2e, r2e, content_emb, We_w, We_b, W1_w, W1_b, W2_w, W2_b,
        A1_w, A1_b, A2_w, A2_b, A3_w, A3_b, Ow_w, Ow_b,
        pu_history, pr_history, lengths, pr_content, out);
    return;
  }

  char* w = (char*)d_ws;
  unsigned short* frag_ws = (unsigned short*)(w + FR_OFF);
  float* post_ws  = (float*)(w + PO_OFF);
  float* abase_ws = (float*)(w + AB_OFF);

  pack_kernel<<<4, 256, 0, stream>>>(W1_w, W2_w, A1_w, A2_w, frag_ws);
  setup_kernel<<<NN, 64, 0, stream>>>(content_emb, pr_content, We_w, We_b,
                                      A1_w, A1_b, post_ws, abase_ws);
  fused_kernel<<<2048, 256, 0, stream>>>(
      u2e, r2e, W1_b, W2_b, A2_b, A3_w, A3_b, Ow_w, Ow_b,
      pu_history, pr_history, lengths, (const short8*)frag_ws,
      post_ws, abase_ws, out);
}

// Round 6
// 236.833 us; speedup vs baseline: 1.1672x; 1.1046x over previous
//
#include <hip/hip_runtime.h>
#include <hip/hip_bf16.h>
#include <math.h>

// PostEncode R6: fused bf16-MFMA chain; spill-free by construction.
// R3-R5 post-mortem: WRITE_SIZE 67-154MB/launch = VGPR scratch spills. Root
// cause: __launch_bounds__ 2nd arg is only a MIN-waves floor; the compiler's
// occupancy heuristic chose 84 VGPRs (6 waves/EU) and spilled ~75 values into
// the per-tile critical path. Fix: amdgpu_waves_per_eu(4,4) pins the budget
// at 128 VGPRs, and liveness is trimmed to ~105:
//  - u2e/r2e pre-converted to bf16 tables in ws -> gathers ARE the MFMA
//    B-frags (no f32 staging regs, no cvt, half the gather bytes)
//  - weights stay in LDS (40KB frags + 1KB biases), per-tile ds_reads kept
//    in-loop via asm-blinded offset
//  - abase loaded per tile as L3 C-init (L1-hot), not held resident
//  - named-register index+gather prefetch (one tile ahead, no arrays)
//  - #pragma unroll 1 on node/tile loops
// 512-thr blocks, grid 512 -> 2 blocks/CU (84KB LDS), 16 waves/CU, all waves
// resident, 4 nodes/wave. Verify: WRITE_SIZE ~13MB, VGPR<=128.

#define NN 16384
#define LL 50
#define EE 64
#define NUE 6400000  // u2e elements (100000*64); r2e bf16 table follows

typedef __attribute__((ext_vector_type(8))) short short8;
typedef __attribute__((ext_vector_type(4))) float f32x4;

static __device__ __forceinline__ unsigned short f2bf(float x) {
  __hip_bfloat16 h = __float2bfloat16(x);
  unsigned short u;
  __builtin_memcpy(&u, &h, 2);
  return u;
}

static __device__ __forceinline__ f32x4 ld4(const float* p) {
  return *(const f32x4*)p;
}

static __device__ __forceinline__ f32x4 relu4(f32x4 a) {
  f32x4 r;
  r[0] = fmaxf(a[0], 0.f); r[1] = fmaxf(a[1], 0.f);
  r[2] = fmaxf(a[2], 0.f); r[3] = fmaxf(a[3], 0.f);
  return r;
}

static __device__ __forceinline__ short8 pack8(f32x4 a, f32x4 b) {
  short8 r;
  r[0] = (short)f2bf(a[0]); r[1] = (short)f2bf(a[1]);
  r[2] = (short)f2bf(a[2]); r[3] = (short)f2bf(a[3]);
  r[4] = (short)f2bf(b[0]); r[5] = (short)f2bf(b[1]);
  r[6] = (short)f2bf(b[2]); r[7] = (short)f2bf(b[3]);
  return r;
}

#define MFMA(A, B, C) __builtin_amdgcn_mfma_f32_16x16x32_bf16((A), (B), (C), 0, 0, 0)

// ---------------- conv: u2e,r2e f32 -> bf16 tables ----------------
__global__ __launch_bounds__(256)
void conv_kernel(const float* __restrict__ u2e, const float* __restrict__ r2e,
                 unsigned short* __restrict__ ur_bf) {
  const int total8 = (NUE + 384) / 8;  // 800048
  for (int i = blockIdx.x * 256 + (int)threadIdx.x; i < total8;
       i += gridDim.x * 256) {
    const long long e0 = (long long)i * 8;
    const float* src = (e0 < NUE) ? (u2e + e0) : (r2e + (e0 - NUE));
    float4 a = *(const float4*)src;
    float4 b = *(const float4*)(src + 4);
    short8 v;
    v[0] = (short)f2bf(a.x); v[1] = (short)f2bf(a.y);
    v[2] = (short)f2bf(a.z); v[3] = (short)f2bf(a.w);
    v[4] = (short)f2bf(b.x); v[5] = (short)f2bf(b.y);
    v[6] = (short)f2bf(b.z); v[7] = (short)f2bf(b.w);
    *reinterpret_cast<short8*>(ur_bf + e0) = v;
  }
}

// ---------------- pack: weights -> frag-ordered bf16 ----------------
// short8 index layout: [0,1024) L1 (mt*4+s)*64+lane ; [1024,1536) L2 ;
// [1536,2048) L3 (A1 rows 0..63) ; [2048,2560) L4. Element j of lane
// (g=lane>>4, c=lane&15):  L1: k=32s+8g+j ; others: k=32s+16(j>>2)+4g+(j&3).
__global__ __launch_bounds__(256)
void pack_kernel(const float* __restrict__ W1_w, const float* __restrict__ W2_w,
                 const float* __restrict__ A1_w, const float* __restrict__ A2_w,
                 unsigned short* __restrict__ frag_ws) {
  int tid = blockIdx.x * blockDim.x + threadIdx.x;
  for (int idx = tid; idx < 2560; idx += gridDim.x * blockDim.x) {
    const float* W;
    int mt, s, lane;
    const bool isL1 = idx < 1024;
    if (isL1) {
      mt = idx >> 8; s = (idx >> 6) & 3; lane = idx & 63; W = W1_w;
    } else {
      int r = idx - 1024;
      int li = r >> 9;
      mt = (r >> 7) & 3; s = (r >> 6) & 1; lane = r & 63;
      W = (li == 0) ? W2_w : (li == 1) ? A1_w : A2_w;
    }
    const int g = lane >> 4, c = lane & 15;
#pragma unroll
    for (int j = 0; j < 8; ++j) {
      const int k = isL1 ? (32 * s + 8 * g + j)
                         : (32 * s + 16 * (j >> 2) + 4 * g + (j & 3));
      frag_ws[idx * 8 + j] = f2bf(W[k * EE + 16 * mt + c]);
    }
  }
}

// ---------------- setup: post + abase (f32) ----------------
__global__ __launch_bounds__(64)
void setup_kernel(const float* __restrict__ content_emb,
                  const int* __restrict__ pr_content,
                  const float* __restrict__ We_w, const float* __restrict__ We_b,
                  const float* __restrict__ A1_w, const float* __restrict__ A1_b,
                  float* __restrict__ post_ws, float* __restrict__ abase_ws) {
  const int n = blockIdx.x;
  const int e = threadIdx.x;
  __shared__ float ce_s[128];
  __shared__ float post_s[64];
  const float* ce = content_emb + (size_t)pr_content[n] * 128;
  ce_s[e] = ce[e];
  ce_s[64 + e] = ce[64 + e];
  __syncthreads();
  float acc = We_b[e];
#pragma unroll 8
  for (int k = 0; k < 128; ++k) acc = fmaf(ce_s[k], We_w[k * EE + e], acc);
  float po = fmaxf(acc, 0.f);
  post_s[e] = po;
  post_ws[n * EE + e] = po;
  __syncthreads();
  float ab = A1_b[e];
#pragma unroll 8
  for (int k = 0; k < 64; ++k) ab = fmaf(post_s[k], A1_w[(64 + k) * EE + e], ab);
  abase_ws[n * EE + e] = ab;
}

// ---------------- fused: LDS-weight MLP chain + online softmax ----------------
__global__
__attribute__((amdgpu_flat_work_group_size(512, 512)))
__attribute__((amdgpu_waves_per_eu(4, 4)))
void fused_kernel(const unsigned short* __restrict__ ur_bf,
                  const float* __restrict__ W1_b, const float* __restrict__ W2_b,
                  const float* __restrict__ A2_b,
                  const float* __restrict__ A3_w, const float* __restrict__ A3_b,
                  const float* __restrict__ Ow_w, const float* __restrict__ Ow_b,
                  const int* __restrict__ pu_history,
                  const int* __restrict__ pr_history,
                  const int* __restrict__ lengths,
                  const short8* __restrict__ pf,
                  const float* __restrict__ post_ws,
                  const float* __restrict__ abase_ws,
                  float* __restrict__ out) {
  const int tid = (int)threadIdx.x;
  const int lane = tid & 63;
  const int g = lane >> 4;
  const int c = lane & 15;
  const int wave = blockIdx.x * 8 + (tid >> 6);
  const int nwaves = gridDim.x * 8;

  // ---- stage packed frags (40KB) + biases (1KB) into LDS ----
  __shared__ short8 wf_s[2560 + 64];
  for (int i = tid; i < 2560; i += 512) wf_s[i] = pf[i];
  if (tid < 64) {
    float* bias_s = (float*)(wf_s + 2560);
    bias_s[tid]       = W1_b[tid];
    bias_s[64 + tid]  = W2_b[tid];
    bias_s[128 + tid] = A2_b[tid];
    bias_s[192 + tid] = A3_w[tid];
  }
  __syncthreads();

  const float b3 = A3_b[0];
  const unsigned short* rbase = ur_bf + NUE;

#pragma unroll 1
  for (int n = wave; n < NN; n += nwaves) {
    const int len = lengths[n];
    const int ntile = (len + 15) >> 4;
    const int base = n * LL;

    // ---- tile-0 gather (indices then frags), tile-1 indices ----
    int pu = pu_history[base + c];
    int pr = pr_history[base + c];
    const unsigned short* ub = ur_bf + (size_t)pu * EE;
    const unsigned short* rb = rbase + (size_t)pr * EE;
    short8 xf0 = *(const short8*)(ub + 8 * g);
    short8 xf1 = *(const short8*)(ub + 32 + 8 * g);
    short8 xf2 = *(const short8*)(rb + 8 * g);
    short8 xf3 = *(const short8*)(rb + 32 + 8 * g);
    int pu_n = pu_history[base + 16 + c];   // t=16+c <= 31 < 50, always valid
    int pr_n = pr_history[base + 16 + c];

    float m = -INFINITY;
    float ssum = 0.f;           // per-lane partial
    f32x4 hacc[4];              // per-lane partial
#pragma unroll
    for (int mt = 0; mt < 4; ++mt) {
      hacc[mt][0] = 0.f; hacc[mt][1] = 0.f;
      hacc[mt][2] = 0.f; hacc[mt][3] = 0.f;
    }

    int wofs = 0;  // blinded each tile: LDS frag reads cannot be hoisted
#pragma unroll 1
    for (int lt = 0; lt < ntile; ++lt) {
      asm volatile("" : "+v"(wofs));
      const short8* wp = wf_s + wofs;
      const float* bp = (const float*)(wf_s + 2560) + wofs;

      // ---- prefetch next tile: gather frags + indices two ahead ----
      short8 nf0, nf1, nf2, nf3;
      const bool more = (lt + 1 < ntile);
      if (more) {
        const unsigned short* ubn = ur_bf + (size_t)pu_n * EE;
        const unsigned short* rbn = rbase + (size_t)pr_n * EE;
        nf0 = *(const short8*)(ubn + 8 * g);
        nf1 = *(const short8*)(ubn + 32 + 8 * g);
        nf2 = *(const short8*)(rbn + 8 * g);
        nf3 = *(const short8*)(rbn + 32 + 8 * g);
        const int t2 = ((lt + 2) << 4) + c;
        const int tc2 = (t2 < LL) ? t2 : 0;   // clamp; unused values masked
        pu_n = pu_history[base + tc2];
        pr_n = pr_history[base + tc2];
      }

      // ---- L1: X1^T = relu(W1^T X^T + b1) ----
      f32x4 acc[4];
#pragma unroll
      for (int mt = 0; mt < 4; ++mt) acc[mt] = ld4(bp + 16 * mt + 4 * g);
#pragma unroll
      for (int mt = 0; mt < 4; ++mt) {
        acc[mt] = MFMA(wp[(mt * 4 + 0) * 64 + lane], xf0, acc[mt]);
        acc[mt] = MFMA(wp[(mt * 4 + 1) * 64 + lane], xf1, acc[mt]);
        acc[mt] = MFMA(wp[(mt * 4 + 2) * 64 + lane], xf2, acc[mt]);
        acc[mt] = MFMA(wp[(mt * 4 + 3) * 64 + lane], xf3, acc[mt]);
      }
#pragma unroll
      for (int mt = 0; mt < 4; ++mt) acc[mt] = relu4(acc[mt]);
      short8 Bf[2];
      Bf[0] = pack8(acc[0], acc[1]);
      Bf[1] = pack8(acc[2], acc[3]);

      // ---- L2: o^T = relu(W2^T X1^T + b2) ----
      f32x4 o_[4];
#pragma unroll
      for (int mt = 0; mt < 4; ++mt) o_[mt] = ld4(bp + 64 + 16 * mt + 4 * g);
#pragma unroll
      for (int s = 0; s < 2; ++s)
#pragma unroll
        for (int mt = 0; mt < 4; ++mt)
          o_[mt] = MFMA(wp[1024 + (mt * 2 + s) * 64 + lane], Bf[s], o_[mt]);
#pragma unroll
      for (int mt = 0; mt < 4; ++mt) o_[mt] = relu4(o_[mt]);
      Bf[0] = pack8(o_[0], o_[1]);
      Bf[1] = pack8(o_[2], o_[3]);

      // ---- L3: a1^T = relu(A1a^T o^T + abase[n]) ----
      f32x4 acc3[4];
#pragma unroll
      for (int mt = 0; mt < 4; ++mt)
        acc3[mt] = ld4(abase_ws + (size_t)n * EE + 16 * mt + 4 * g);
#pragma unroll
      for (int s = 0; s < 2; ++s)
#pragma unroll
        for (int mt = 0; mt < 4; ++mt)
          acc3[mt] = MFMA(wp[1536 + (mt * 2 + s) * 64 + lane], Bf[s], acc3[mt]);
#pragma unroll
      for (int mt = 0; mt < 4; ++mt) acc3[mt] = relu4(acc3[mt]);
      Bf[0] = pack8(acc3[0], acc3[1]);
      Bf[1] = pack8(acc3[2], acc3[3]);

      // ---- L4: a2^T = relu(A2^T a1^T + b); logit = a2 . A3 + b3 ----
      f32x4 acc4[4];
#pragma unroll
      for (int mt = 0; mt < 4; ++mt) acc4[mt] = ld4(bp + 128 + 16 * mt + 4 * g);
#pragma unroll
      for (int s = 0; s < 2; ++s)
#pragma unroll
        for (int mt = 0; mt < 4; ++mt)
          acc4[mt] = MFMA(wp[2048 + (mt * 2 + s) * 64 + lane], Bf[s], acc4[mt]);

      float part = 0.f;
#pragma unroll
      for (int mt = 0; mt < 4; ++mt) {
        f32x4 a3 = ld4(bp + 192 + 16 * mt + 4 * g);
        f32x4 r = relu4(acc4[mt]);
        part = fmaf(r[0], a3[0], part);
        part = fmaf(r[1], a3[1], part);
        part = fmaf(r[2], a3[2], part);
        part = fmaf(r[3], a3[3], part);
      }
      part += __shfl_xor(part, 16);
      part += __shfl_xor(part, 32);  // logit for this lane's row (c)

      const int t = (lt << 4) + c;
      const float lg = (t < len) ? (part + b3) : -INFINITY;

      // tile max over c -> uniform across the wave
      float tm = lg;
      tm = fmaxf(tm, __shfl_xor(tm, 1));
      tm = fmaxf(tm, __shfl_xor(tm, 2));
      tm = fmaxf(tm, __shfl_xor(tm, 4));
      tm = fmaxf(tm, __shfl_xor(tm, 8));

      const float m_new = fmaxf(m, tm);
      const float scale = __expf(m - m_new);  // 0 on first tile
      const float w = __expf(lg - m_new);     // 0 for masked rows

      ssum = ssum * scale + w;                // per-lane partial
#pragma unroll
      for (int mt = 0; mt < 4; ++mt) {        // per-lane partials, no shuffles
        hacc[mt][0] = fmaf(w, o_[mt][0], hacc[mt][0] * scale);
        hacc[mt][1] = fmaf(w, o_[mt][1], hacc[mt][1] * scale);
        hacc[mt][2] = fmaf(w, o_[mt][2], hacc[mt][2] * scale);
        hacc[mt][3] = fmaf(w, o_[mt][3], hacc[mt][3] * scale);
      }
      m = m_new;

      // rotate prefetched gather into place
      if (more) { xf0 = nf0; xf1 = nf1; xf2 = nf2; xf3 = nf3; }
    }

    // ---- node-end reductions over c (butterfly; all lanes get sums) ----
    float sv = ssum;
    sv += __shfl_xor(sv, 1);
    sv += __shfl_xor(sv, 2);
    sv += __shfl_xor(sv, 4);
    sv += __shfl_xor(sv, 8);
    const float inv = 1.f / sv;

    float hred[4][4];
#pragma unroll
    for (int mt = 0; mt < 4; ++mt)
#pragma unroll
      for (int r = 0; r < 4; ++r) {
        float v = hacc[mt][r];
        v += __shfl_xor(v, 1);
        v += __shfl_xor(v, 2);
        v += __shfl_xor(v, 4);
        v += __shfl_xor(v, 8);
        hred[mt][r] = v * inv;   // hist[16mt+4g+r], valid on all lanes
      }

    // ---- epilogue: out = relu([hist;post] @ Ow + b), pure shfl ----
    const float po = post_ws[(size_t)n * EE + lane];
    float acc = Ow_b[lane];
#pragma unroll
    for (int k = 0; k < 64; ++k) {
      const int mt = k >> 4, gk = (k >> 2) & 3, r = k & 3;
      const float hk = __shfl(hred[mt][r], gk << 4);
      acc = fmaf(hk, Ow_w[k * EE + lane], acc);
    }
#pragma unroll 8
    for (int k = 0; k < 64; ++k)
      acc = fmaf(__shfl(po, k), Ow_w[(64 + k) * EE + lane], acc);
    out[(size_t)n * EE + lane] = fmaxf(acc, 0.f);
  }
}

// ---------------- R1 fallback (all-f32, no workspace) ----------------
template <int K>
__device__ __forceinline__ void mm2(const float* row0, const float* row1,
                                    const float* __restrict__ W, int e,
                                    float& acc0, float& acc1) {
  const float4* r0 = (const float4*)row0;
  const float4* r1 = (const float4*)row1;
#pragma unroll 4
  for (int k4 = 0; k4 < K / 4; ++k4) {
    float4 va = r0[k4];
    float4 vb = r1[k4];
    const float* w = W + (k4 * 4) * EE + e;
    float w0 = w[0], w1 = w[EE], w2 = w[2 * EE], w3 = w[3 * EE];
    acc0 = fmaf(va.x, w0, acc0);  acc1 = fmaf(vb.x, w0, acc1);
    acc0 = fmaf(va.y, w1, acc0);  acc1 = fmaf(vb.y, w1, acc1);
    acc0 = fmaf(va.z, w2, acc0);  acc1 = fmaf(vb.z, w2, acc1);
    acc0 = fmaf(va.w, w3, acc0);  acc1 = fmaf(vb.w, w3, acc1);
  }
}

__global__ __launch_bounds__(256, 4)
void postenc_kernel(
    const float* __restrict__ u2e, const float* __restrict__ r2e,
    const float* __restrict__ content_emb,
    const float* __restrict__ We_w, const float* __restrict__ We_b,
    const float* __restrict__ W1_w, const float* __restrict__ W1_b,
    const float* __restrict__ W2_w, const float* __restrict__ W2_b,
    const float* __restrict__ A1_w, const float* __restrict__ A1_b,
    const float* __restrict__ A2_w, const float* __restrict__ A2_b,
    const float* __restrict__ A3_w, const float* __restrict__ A3_b,
    const float* __restrict__ Ow_w, const float* __restrict__ Ow_b,
    const int* __restrict__ pu_history, const int* __restrict__ pr_history,
    const int* __restrict__ lengths, const int* __restrict__ pr_content,
    float* __restrict__ out) {
  const int n = blockIdx.x;
  const int tid = (int)threadIdx.x;
  const int e = tid & 63;
  const int g = tid >> 6;

  __shared__ float post_s[EE];
  __shared__ float abase_s[EE];
  __shared__ float in_s[8][128];
  __shared__ float x_s[8][EE];
  __shared__ float a_s[8][EE];
  __shared__ float o_s[56][EE];
  __shared__ float logit_s[EE];
  __shared__ float att_s[EE];
  __shared__ float red_s[4][EE];

  const int len = lengths[n];
  float p = 0.f;

  if (g == 0) {
    const float* ce = content_emb + (size_t)pr_content[n] * 128;
    float acc = We_b[e];
#pragma unroll 4
    for (int k = 0; k < 128; ++k) acc = fmaf(ce[k], We_w[k * EE + e], acc);
    p = fmaxf(acc, 0.f);
    post_s[e] = p;
    float ab = A1_b[e];
#pragma unroll
    for (int k = 0; k < 64; ++k) {
      float pk = __shfl(p, k);
      ab = fmaf(pk, A1_w[(64 + k) * EE + e], ab);
    }
    abase_s[e] = ab;
    logit_s[e] = -INFINITY;
  }
  __syncthreads();

  for (int lb = 0; lb < 56; lb += 8) {
    const int l0 = lb + g;
    const int l1 = l0 + 4;
    const bool v0 = l0 < LL;
    const bool v1 = l1 < LL;

    int pu0 = 0, pr0 = 0, pu1 = 0, pr1 = 0;
    if (v0) { pu0 = pu_history[n * LL + l0]; pr0 = pr_history[n * LL + l0]; }
    if (v1) { pu1 = pu_history[n * LL + l1]; pr1 = pr_history[n * LL + l1]; }
    in_s[g][e]          = v0 ? u2e[(size_t)pu0 * EE + e] : 0.f;
    in_s[g][64 + e]     = v0 ? r2e[pr0 * EE + e]         : 0.f;
    in_s[g + 4][e]      = v1 ? u2e[(size_t)pu1 * EE + e] : 0.f;
    in_s[g + 4][64 + e] = v1 ? r2e[pr1 * EE + e]         : 0.f;
    __syncthreads();

    float acc0 = W1_b[e], acc1 = acc0;
    mm2<128>(in_s[g], in_s[g + 4], W1_w, e, acc0, acc1);
    x_s[g][e]     = fmaxf(acc0, 0.f);
    x_s[g + 4][e] = fmaxf(acc1, 0.f);
    __syncthreads();

    acc0 = W2_b[e]; acc1 = acc0;
    mm2<64>(x_s[g], x_s[g + 4], W2_w, e, acc0, acc1);
    float o0 = fmaxf(acc0, 0.f);
    float o1 = fmaxf(acc1, 0.f);
    if (v0) o_s[l0][e] = o0;
    if (v1) o_s[l1][e] = o1;
    x_s[g][e]     = o0;
    x_s[g + 4][e] = o1;
    __syncthreads();

    acc0 = abase_s[e]; acc1 = acc0;
    mm2<64>(x_s[g], x_s[g + 4], A1_w, e, acc0, acc1);
    a_s[g][e]     = fmaxf(acc0, 0.f);
    a_s[g + 4][e] = fmaxf(acc1, 0.f);
    __syncthreads();

    acc0 = A2_b[e]; acc1 = acc0;
    mm2<64>(a_s[g], a_s[g + 4], A2_w, e, acc0, acc1);
    float w3 = A3_w[e];
    float p0 = fmaxf(acc0, 0.f) * w3;
    float p1 = fmaxf(acc1, 0.f) * w3;
#pragma unroll
    for (int off = 32; off > 0; off >>= 1) {
      p0 += __shfl_xor(p0, off);
      p1 += __shfl_xor(p1, off);
    }
    if (e == 0) {
      float b3 = A3_b[0];
      if (l0 < len) logit_s[l0] = p0 + b3;
      if (l1 < len) logit_s[l1] = p1 + b3;
    }
    __syncthreads();
  }

  if (g == 0) {
    float lg = logit_s[e];
    float m = lg;
#pragma unroll
    for (int off = 32; off > 0; off >>= 1) m = fmaxf(m, __shfl_xor(m, off));
    float pe = __expf(lg - m);
    float sm = pe;
#pragma unroll
    for (int off = 32; off > 0; off >>= 1) sm += __shfl_xor(sm, off);
    att_s[e] = pe / sm;
  }
  __syncthreads();

  {
    const int l_lo = 13 * g;
    const int l_hi = (13 * g + 13 < LL) ? 13 * g + 13 : LL;
    float h = 0.f;
    for (int l = l_lo; l < l_hi; ++l) h = fmaf(att_s[l], o_s[l][e], h);
    red_s[g][e] = h;
  }
  __syncthreads();

  if (g == 0) {
    float h = red_s[0][e] + red_s[1][e] + red_s[2][e] + red_s[3][e];
    float acc = Ow_b[e];
#pragma unroll
    for (int k = 0; k < 64; ++k) {
      float hk = __shfl(h, k);
      acc = fmaf(hk, Ow_w[k * EE + e], acc);
    }
#pragma unroll
    for (int k = 0; k < 64; ++k) {
      float pk = __shfl(p, k);
      acc = fmaf(pk, Ow_w[(64 + k) * EE + e], acc);
    }
    out[(size_t)n * EE + e] = fmaxf(acc, 0.f);
  }
}

// ---------------- launcher ----------------
extern "C" void kernel_launch(void* const* d_in, const int* in_sizes, int n_in,
                              void* d_out, int out_size, void* d_ws, size_t ws_size,
                              hipStream_t stream) {
  const float* u2e         = (const float*)d_in[0];
  const float* r2e         = (const float*)d_in[1];
  const float* content_emb = (const float*)d_in[2];
  const float* We_w = (const float*)d_in[3];
  const float* We_b = (const float*)d_in[4];
  const float* W1_w = (const float*)d_in[5];
  const float* W1_b = (const float*)d_in[6];
  const float* W2_w = (const float*)d_in[7];
  const float* W2_b = (const float*)d_in[8];
  const float* A1_w = (const float*)d_in[9];
  const float* A1_b = (const float*)d_in[10];
  const float* A2_w = (const float*)d_in[11];
  const float* A2_b = (const float*)d_in[12];
  const float* A3_w = (const float*)d_in[13];
  const float* A3_b = (const float*)d_in[14];
  const float* Ow_w = (const float*)d_in[15];
  const float* Ow_b = (const float*)d_in[16];
  // d_in[17] = nodes (unused)
  const int* pu_history = (const int*)d_in[18];
  const int* pr_history = (const int*)d_in[19];
  const int* lengths    = (const int*)d_in[20];
  const int* pr_content = (const int*)d_in[21];
  float* out = (float*)d_out;

  // workspace layout (bytes)
  const size_t FR_OFF  = 0;                        // 2560 short8 = 40960 B
  const size_t PO_OFF  = 65536;                    // post f32 [N*64]
  const size_t AB_OFF  = PO_OFF + (size_t)NN * EE * 4;
  const size_t UBF_OFF = AB_OFF + (size_t)NN * EE * 4;   // bf16 u2e+r2e tables
  const size_t NEED    = UBF_OFF + (size_t)(NUE + 384) * 2;  // ~21.3 MB

  if (ws_size < NEED) {
    postenc_kernel<<<NN, 256, 0, stream>>>(
        u2e, r2e, content_emb, We_w, We_b, W1_w, W1_b, W2_w, W2_b,
        A1_w, A1_b, A2_w, A2_b, A3_w, A3_b, Ow_w, Ow_b,
        pu_history, pr_history, lengths, pr_content, out);
    return;
  }

  char* w = (char*)d_ws;
  unsigned short* frag_ws = (unsigned short*)(w + FR_OFF);
  float* post_ws  = (float*)(w + PO_OFF);
  float* abase_ws = (float*)(w + AB_OFF);
  unsigned short* ur_bf = (unsigned short*)(w + UBF_OFF);

  conv_kernel<<<2048, 256, 0, stream>>>(u2e, r2e, ur_bf);
  pack_kernel<<<4, 256, 0, stream>>>(W1_w, W2_w, A1_w, A2_w, frag_ws);
  setup_kernel<<<NN, 64, 0, stream>>>(content_emb, pr_content, We_w, We_b,
                                      A1_w, A1_b, post_ws, abase_ws);
  fused_kernel<<<512, 512, 0, stream>>>(
      ur_bf, W1_b, W2_b, A2_b, A3_w, A3_b, Ow_w, Ow_b,
      pu_history, pr_history, lengths, (const short8*)frag_ws,
      post_ws, abase_ws, out);
}

// Round 7
// 199.637 us; speedup vs baseline: 1.3847x; 1.1863x over previous
//
#include <hip/hip_runtime.h>
#include <hip/hip_bf16.h>
#include <math.h>

// PostEncode R7: fused bf16-MFMA chain, liveness-minimized (~70 VGPR).
// R3-R6 post-mortem: every variant spilled (WRITE_SIZE 67-154MB = scratch)
// because true per-lane liveness (~150) exceeded whatever budget the
// allocator picked (64-128). R7 shrinks liveness below ANY plausible budget:
//  - no data prefetch (TLP hides gather latency; only 2-reg index prefetch)
//  - o kept as bf16 B-frag copy (8 regs) instead of f32x4[4] (16 regs);
//    unpacked by <<16 at the hacc update (numerics = R2, validated)
//  - weights in LDS (40KB frags + 1KB biases), per-tile reads asm-blinded
//  - amdgpu_waves_per_eu(3,3): 170-VGPR budget, consistent with the LDS
//    limit (42KB -> 3 blocks/CU x 4 waves = 12 waves/CU = 3/SIMD)
// Verify: fused WRITE_SIZE ~12MB, no scratch.

#define NN 16384
#define LL 50
#define EE 64
#define NUE 6400000  // u2e elements (100000*64); r2e bf16 table follows

typedef __attribute__((ext_vector_type(8))) short short8;
typedef __attribute__((ext_vector_type(4))) float f32x4;

static __device__ __forceinline__ unsigned short f2bf(float x) {
  __hip_bfloat16 h = __float2bfloat16(x);
  unsigned short u;
  __builtin_memcpy(&u, &h, 2);
  return u;
}

static __device__ __forceinline__ float bf2f(unsigned short u) {
  unsigned int v = ((unsigned int)u) << 16;
  float f;
  __builtin_memcpy(&f, &v, 4);
  return f;
}

static __device__ __forceinline__ f32x4 ld4(const float* p) {
  return *(const f32x4*)p;
}

static __device__ __forceinline__ f32x4 relu4(f32x4 a) {
  f32x4 r;
  r[0] = fmaxf(a[0], 0.f); r[1] = fmaxf(a[1], 0.f);
  r[2] = fmaxf(a[2], 0.f); r[3] = fmaxf(a[3], 0.f);
  return r;
}

static __device__ __forceinline__ short8 pack8(f32x4 a, f32x4 b) {
  short8 r;
  r[0] = (short)f2bf(a[0]); r[1] = (short)f2bf(a[1]);
  r[2] = (short)f2bf(a[2]); r[3] = (short)f2bf(a[3]);
  r[4] = (short)f2bf(b[0]); r[5] = (short)f2bf(b[1]);
  r[6] = (short)f2bf(b[2]); r[7] = (short)f2bf(b[3]);
  return r;
}

#define MFMA(A, B, C) __builtin_amdgcn_mfma_f32_16x16x32_bf16((A), (B), (C), 0, 0, 0)

// ---------------- conv: u2e,r2e f32 -> bf16 tables ----------------
__global__ __launch_bounds__(256)
void conv_kernel(const float* __restrict__ u2e, const float* __restrict__ r2e,
                 unsigned short* __restrict__ ur_bf) {
  const int total8 = (NUE + 384) / 8;  // 800048
  for (int i = blockIdx.x * 256 + (int)threadIdx.x; i < total8;
       i += gridDim.x * 256) {
    const long long e0 = (long long)i * 8;
    const float* src = (e0 < NUE) ? (u2e + e0) : (r2e + (e0 - NUE));
    float4 a = *(const float4*)src;
    float4 b = *(const float4*)(src + 4);
    short8 v;
    v[0] = (short)f2bf(a.x); v[1] = (short)f2bf(a.y);
    v[2] = (short)f2bf(a.z); v[3] = (short)f2bf(a.w);
    v[4] = (short)f2bf(b.x); v[5] = (short)f2bf(b.y);
    v[6] = (short)f2bf(b.z); v[7] = (short)f2bf(b.w);
    *reinterpret_cast<short8*>(ur_bf + e0) = v;
  }
}

// ---------------- pack: weights -> frag-ordered bf16 ----------------
// short8 index layout: [0,1024) L1 (mt*4+s)*64+lane ; [1024,1536) L2 ;
// [1536,2048) L3 (A1 rows 0..63) ; [2048,2560) L4. Element j of lane
// (g=lane>>4, c=lane&15):  L1: k=32s+8g+j ; others: k=32s+16(j>>2)+4g+(j&3).
__global__ __launch_bounds__(256)
void pack_kernel(const float* __restrict__ W1_w, const float* __restrict__ W2_w,
                 const float* __restrict__ A1_w, const float* __restrict__ A2_w,
                 unsigned short* __restrict__ frag_ws) {
  int tid = blockIdx.x * blockDim.x + threadIdx.x;
  for (int idx = tid; idx < 2560; idx += gridDim.x * blockDim.x) {
    const float* W;
    int mt, s, lane;
    const bool isL1 = idx < 1024;
    if (isL1) {
      mt = idx >> 8; s = (idx >> 6) & 3; lane = idx & 63; W = W1_w;
    } else {
      int r = idx - 1024;
      int li = r >> 9;
      mt = (r >> 7) & 3; s = (r >> 6) & 1; lane = r & 63;
      W = (li == 0) ? W2_w : (li == 1) ? A1_w : A2_w;
    }
    const int g = lane >> 4, c = lane & 15;
#pragma unroll
    for (int j = 0; j < 8; ++j) {
      const int k = isL1 ? (32 * s + 8 * g + j)
                         : (32 * s + 16 * (j >> 2) + 4 * g + (j & 3));
      frag_ws[idx * 8 + j] = f2bf(W[k * EE + 16 * mt + c]);
    }
  }
}

// ---------------- setup: post + abase (f32) ----------------
__global__ __launch_bounds__(64)
void setup_kernel(const float* __restrict__ content_emb,
                  const int* __restrict__ pr_content,
                  const float* __restrict__ We_w, const float* __restrict__ We_b,
                  const float* __restrict__ A1_w, const float* __restrict__ A1_b,
                  float* __restrict__ post_ws, float* __restrict__ abase_ws) {
  const int n = blockIdx.x;
  const int e = threadIdx.x;
  __shared__ float ce_s[128];
  __shared__ float post_s[64];
  const float* ce = content_emb + (size_t)pr_content[n] * 128;
  ce_s[e] = ce[e];
  ce_s[64 + e] = ce[64 + e];
  __syncthreads();
  float acc = We_b[e];
#pragma unroll 8
  for (int k = 0; k < 128; ++k) acc = fmaf(ce_s[k], We_w[k * EE + e], acc);
  float po = fmaxf(acc, 0.f);
  post_s[e] = po;
  post_ws[n * EE + e] = po;
  __syncthreads();
  float ab = A1_b[e];
#pragma unroll 8
  for (int k = 0; k < 64; ++k) ab = fmaf(post_s[k], A1_w[(64 + k) * EE + e], ab);
  abase_ws[n * EE + e] = ab;
}

// ---------------- fused: LDS-weight MLP chain + online softmax ----------------
__global__
__attribute__((amdgpu_flat_work_group_size(256, 256)))
__attribute__((amdgpu_waves_per_eu(3, 3)))
void fused_kernel(const unsigned short* __restrict__ ur_bf,
                  const float* __restrict__ W1_b, const float* __restrict__ W2_b,
                  const float* __restrict__ A2_b,
                  const float* __restrict__ A3_w, const float* __restrict__ A3_b,
                  const float* __restrict__ Ow_w, const float* __restrict__ Ow_b,
                  const int* __restrict__ pu_history,
                  const int* __restrict__ pr_history,
                  const int* __restrict__ lengths,
                  const short8* __restrict__ pf,
                  const float* __restrict__ post_ws,
                  const float* __restrict__ abase_ws,
                  float* __restrict__ out) {
  const int tid = (int)threadIdx.x;
  const int lane = tid & 63;
  const int g = lane >> 4;
  const int c = lane & 15;
  const int wave = blockIdx.x * 4 + (tid >> 6);
  const int nwaves = gridDim.x * 4;

  // ---- stage packed frags (40KB) + biases (1KB) into LDS ----
  __shared__ short8 wf_s[2560 + 64];
  for (int i = tid; i < 2560; i += 256) wf_s[i] = pf[i];
  if (tid < 64) {
    float* bias_s = (float*)(wf_s + 2560);
    bias_s[tid]       = W1_b[tid];
    bias_s[64 + tid]  = W2_b[tid];
    bias_s[128 + tid] = A2_b[tid];
    bias_s[192 + tid] = A3_w[tid];
  }
  __syncthreads();

  const float b3 = A3_b[0];
  const unsigned short* rbase = ur_bf + NUE;

#pragma unroll 1
  for (int n = wave; n < NN; n += nwaves) {
    const int len = lengths[n];
    const int ntile = (len + 15) >> 4;
    const int base = n * LL;

    int pu = pu_history[base + c];   // tile-0 indices (c<16 always valid)
    int pr = pr_history[base + c];

    float m = -INFINITY;
    float ssum = 0.f;           // per-lane partial
    f32x4 hacc[4];              // per-lane partial
#pragma unroll
    for (int mt = 0; mt < 4; ++mt) {
      hacc[mt][0] = 0.f; hacc[mt][1] = 0.f;
      hacc[mt][2] = 0.f; hacc[mt][3] = 0.f;
    }

    int wofs = 0;  // blinded each tile: LDS frag reads cannot be hoisted
#pragma unroll 1
    for (int lt = 0; lt < ntile; ++lt) {
      asm volatile("" : "+v"(wofs));
      const short8* wp = wf_s + wofs;
      const float* bp = (const float*)(wf_s + 2560) + wofs;

      // ---- gather this tile's rows (bf16 frags, direct) ----
      const unsigned short* ub = ur_bf + (size_t)pu * EE;
      const unsigned short* rb = rbase + (size_t)pr * EE;
      short8 xf0 = *(const short8*)(ub + 8 * g);
      short8 xf1 = *(const short8*)(ub + 32 + 8 * g);
      short8 xf2 = *(const short8*)(rb + 8 * g);
      short8 xf3 = *(const short8*)(rb + 32 + 8 * g);

      // ---- prefetch next tile's indices (2 regs) ----
      {
        const int t2 = ((lt + 1) << 4) + c;
        const int tc2 = (t2 < LL) ? t2 : 0;
        pu = pu_history[base + tc2];
        pr = pr_history[base + tc2];
      }

      // ---- L1: X1^T = relu(W1^T X^T + b1) ----
      f32x4 acc[4];
#pragma unroll
      for (int mt = 0; mt < 4; ++mt) acc[mt] = ld4(bp + 16 * mt + 4 * g);
#pragma unroll
      for (int mt = 0; mt < 4; ++mt) {
        acc[mt] = MFMA(wp[(mt * 4 + 0) * 64 + lane], xf0, acc[mt]);
        acc[mt] = MFMA(wp[(mt * 4 + 1) * 64 + lane], xf1, acc[mt]);
        acc[mt] = MFMA(wp[(mt * 4 + 2) * 64 + lane], xf2, acc[mt]);
        acc[mt] = MFMA(wp[(mt * 4 + 3) * 64 + lane], xf3, acc[mt]);
      }
#pragma unroll
      for (int mt = 0; mt < 4; ++mt) acc[mt] = relu4(acc[mt]);
      short8 Bf[2];
      Bf[0] = pack8(acc[0], acc[1]);
      Bf[1] = pack8(acc[2], acc[3]);

      // ---- L2: o^T = relu(W2^T X1^T + b2) ----
#pragma unroll
      for (int mt = 0; mt < 4; ++mt) acc[mt] = ld4(bp + 64 + 16 * mt + 4 * g);
#pragma unroll
      for (int s = 0; s < 2; ++s)
#pragma unroll
        for (int mt = 0; mt < 4; ++mt)
          acc[mt] = MFMA(wp[1024 + (mt * 2 + s) * 64 + lane], Bf[s], acc[mt]);
#pragma unroll
      for (int mt = 0; mt < 4; ++mt) acc[mt] = relu4(acc[mt]);
      // o in bf16 frag form; keep an 8-reg copy for the hacc update
      const short8 Bo0 = pack8(acc[0], acc[1]);
      const short8 Bo1 = pack8(acc[2], acc[3]);
      Bf[0] = Bo0;
      Bf[1] = Bo1;

      // ---- L3: a1^T = relu(A1a^T o^T + abase[n]) ----
#pragma unroll
      for (int mt = 0; mt < 4; ++mt)
        acc[mt] = ld4(abase_ws + (size_t)n * EE + 16 * mt + 4 * g);
#pragma unroll
      for (int s = 0; s < 2; ++s)
#pragma unroll
        for (int mt = 0; mt < 4; ++mt)
          acc[mt] = MFMA(wp[1536 + (mt * 2 + s) * 64 + lane], Bf[s], acc[mt]);
#pragma unroll
      for (int mt = 0; mt < 4; ++mt) acc[mt] = relu4(acc[mt]);
      Bf[0] = pack8(acc[0], acc[1]);
      Bf[1] = pack8(acc[2], acc[3]);

      // ---- L4: a2^T = relu(A2^T a1^T + b); logit = a2 . A3 + b3 ----
#pragma unroll
      for (int mt = 0; mt < 4; ++mt) acc[mt] = ld4(bp + 128 + 16 * mt + 4 * g);
#pragma unroll
      for (int s = 0; s < 2; ++s)
#pragma unroll
        for (int mt = 0; mt < 4; ++mt)
          acc[mt] = MFMA(wp[2048 + (mt * 2 + s) * 64 + lane], Bf[s], acc[mt]);

      float part = 0.f;
#pragma unroll
      for (int mt = 0; mt < 4; ++mt) {
        f32x4 a3 = ld4(bp + 192 + 16 * mt + 4 * g);
        f32x4 r = relu4(acc[mt]);
        part = fmaf(r[0], a3[0], part);
        part = fmaf(r[1], a3[1], part);
        part = fmaf(r[2], a3[2], part);
        part = fmaf(r[3], a3[3], part);
      }
      part += __shfl_xor(part, 16);
      part += __shfl_xor(part, 32);  // logit for this lane's row (c)

      const int t = (lt << 4) + c;
      const float lg = (t < len) ? (part + b3) : -INFINITY;

      // tile max over c -> uniform across the wave
      float tm = lg;
      tm = fmaxf(tm, __shfl_xor(tm, 1));
      tm = fmaxf(tm, __shfl_xor(tm, 2));
      tm = fmaxf(tm, __shfl_xor(tm, 4));
      tm = fmaxf(tm, __shfl_xor(tm, 8));

      const float m_new = fmaxf(m, tm);
      const float scale = __expf(m - m_new);  // 0 on first tile
      const float w = __expf(lg - m_new);     // 0 for masked rows

      ssum = ssum * scale + w;                // per-lane partial
      // hacc update from bf16 o copy (static indexing, unrolled)
#pragma unroll
      for (int mt = 0; mt < 4; ++mt) {
#pragma unroll
        for (int r = 0; r < 4; ++r) {
          const short ov = (mt < 2) ? Bo0[4 * (mt & 1) + r] : Bo1[4 * (mt & 1) + r];
          const float os = bf2f((unsigned short)ov);
          hacc[mt][r] = fmaf(w, os, hacc[mt][r] * scale);
        }
      }
      m = m_new;
    }

    // ---- node-end reductions over c (butterfly; all lanes get sums) ----
    float sv = ssum;
    sv += __shfl_xor(sv, 1);
    sv += __shfl_xor(sv, 2);
    sv += __shfl_xor(sv, 4);
    sv += __shfl_xor(sv, 8);
    const float inv = 1.f / sv;

    float hred[4][4];
#pragma unroll
    for (int mt = 0; mt < 4; ++mt)
#pragma unroll
      for (int r = 0; r < 4; ++r) {
        float v = hacc[mt][r];
        v += __shfl_xor(v, 1);
        v += __shfl_xor(v, 2);
        v += __shfl_xor(v, 4);
        v += __shfl_xor(v, 8);
        hred[mt][r] = v * inv;   // hist[16mt+4g+r], valid on all lanes
      }

    // ---- epilogue: out = relu([hist;post] @ Ow + b), pure shfl ----
    const float po = post_ws[(size_t)n * EE + lane];
    float acc = Ow_b[lane];
#pragma unroll
    for (int k = 0; k < 64; ++k) {
      const int mt = k >> 4, gk = (k >> 2) & 3, r = k & 3;
      const float hk = __shfl(hred[mt][r], gk << 4);
      acc = fmaf(hk, Ow_w[k * EE + lane], acc);
    }
#pragma unroll 8
    for (int k = 0; k < 64; ++k)
      acc = fmaf(__shfl(po, k), Ow_w[(64 + k) * EE + lane], acc);
    out[(size_t)n * EE + lane] = fmaxf(acc, 0.f);
  }
}

// ---------------- R1 fallback (all-f32, no workspace) ----------------
template <int K>
__device__ __forceinline__ void mm2(const float* row0, const float* row1,
                                    const float* __restrict__ W, int e,
                                    float& acc0, float& acc1) {
  const float4* r0 = (const float4*)row0;
  const float4* r1 = (const float4*)row1;
#pragma unroll 4
  for (int k4 = 0; k4 < K / 4; ++k4) {
    float4 va = r0[k4];
    float4 vb = r1[k4];
    const float* w = W + (k4 * 4) * EE + e;
    float w0 = w[0], w1 = w[EE], w2 = w[2 * EE], w3 = w[3 * EE];
    acc0 = fmaf(va.x, w0, acc0);  acc1 = fmaf(vb.x, w0, acc1);
    acc0 = fmaf(va.y, w1, acc0);  acc1 = fmaf(vb.y, w1, acc1);
    acc0 = fmaf(va.z, w2, acc0);  acc1 = fmaf(vb.z, w2, acc1);
    acc0 = fmaf(va.w, w3, acc0);  acc1 = fmaf(vb.w, w3, acc1);
  }
}

__global__ __launch_bounds__(256, 4)
void postenc_kernel(
    const float* __restrict__ u2e, const float* __restrict__ r2e,
    const float* __restrict__ content_emb,
    const float* __restrict__ We_w, const float* __restrict__ We_b,
    const float* __restrict__ W1_w, const float* __restrict__ W1_b,
    const float* __restrict__ W2_w, const float* __restrict__ W2_b,
    const float* __restrict__ A1_w, const float* __restrict__ A1_b,
    const float* __restrict__ A2_w, const float* __restrict__ A2_b,
    const float* __restrict__ A3_w, const float* __restrict__ A3_b,
    const float* __restrict__ Ow_w, const float* __restrict__ Ow_b,
    const int* __restrict__ pu_history, const int* __restrict__ pr_history,
    const int* __restrict__ lengths, const int* __restrict__ pr_content,
    float* __restrict__ out) {
  const int n = blockIdx.x;
  const int tid = (int)threadIdx.x;
  const int e = tid & 63;
  const int g = tid >> 6;

  __shared__ float post_s[EE];
  __shared__ float abase_s[EE];
  __shared__ float in_s[8][128];
  __shared__ float x_s[8][EE];
  __shared__ float a_s[8][EE];
  __shared__ float o_s[56][EE];
  __shared__ float logit_s[EE];
  __shared__ float att_s[EE];
  __shared__ float red_s[4][EE];

  const int len = lengths[n];
  float p = 0.f;

  if (g == 0) {
    const float* ce = content_emb + (size_t)pr_content[n] * 128;
    float acc = We_b[e];
#pragma unroll 4
    for (int k = 0; k < 128; ++k) acc = fmaf(ce[k], We_w[k * EE + e], acc);
    p = fmaxf(acc, 0.f);
    post_s[e] = p;
    float ab = A1_b[e];
#pragma unroll
    for (int k = 0; k < 64; ++k) {
      float pk = __shfl(p, k);
      ab = fmaf(pk, A1_w[(64 + k) * EE + e], ab);
    }
    abase_s[e] = ab;
    logit_s[e] = -INFINITY;
  }
  __syncthreads();

  for (int lb = 0; lb < 56; lb += 8) {
    const int l0 = lb + g;
    const int l1 = l0 + 4;
    const bool v0 = l0 < LL;
    const bool v1 = l1 < LL;

    int pu0 = 0, pr0 = 0, pu1 = 0, pr1 = 0;
    if (v0) { pu0 = pu_history[n * LL + l0]; pr0 = pr_history[n * LL + l0]; }
    if (v1) { pu1 = pu_history[n * LL + l1]; pr1 = pr_history[n * LL + l1]; }
    in_s[g][e]          = v0 ? u2e[(size_t)pu0 * EE + e] : 0.f;
    in_s[g][64 + e]     = v0 ? r2e[pr0 * EE + e]         : 0.f;
    in_s[g + 4][e]      = v1 ? u2e[(size_t)pu1 * EE + e] : 0.f;
    in_s[g + 4][64 + e] = v1 ? r2e[pr1 * EE + e]         : 0.f;
    __syncthreads();

    float acc0 = W1_b[e], acc1 = acc0;
    mm2<128>(in_s[g], in_s[g + 4], W1_w, e, acc0, acc1);
    x_s[g][e]     = fmaxf(acc0, 0.f);
    x_s[g + 4][e] = fmaxf(acc1, 0.f);
    __syncthreads();

    acc0 = W2_b[e]; acc1 = acc0;
    mm2<64>(x_s[g], x_s[g + 4], W2_w, e, acc0, acc1);
    float o0 = fmaxf(acc0, 0.f);
    float o1 = fmaxf(acc1, 0.f);
    if (v0) o_s[l0][e] = o0;
    if (v1) o_s[l1][e] = o1;
    x_s[g][e]     = o0;
    x_s[g + 4][e] = o1;
    __syncthreads();

    acc0 = abase_s[e]; acc1 = acc0;
    mm2<64>(x_s[g], x_s[g + 4], A1_w, e, acc0, acc1);
    a_s[g][e]     = fmaxf(acc0, 0.f);
    a_s[g + 4][e] = fmaxf(acc1, 0.f);
    __syncthreads();

    acc0 = A2_b[e]; acc1 = acc0;
    mm2<64>(a_s[g], a_s[g + 4], A2_w, e, acc0, acc1);
    float w3 = A3_w[e];
    float p0 = fmaxf(acc0, 0.f) * w3;
    float p1 = fmaxf(acc1, 0.f) * w3;
#pragma unroll
    for (int off = 32; off > 0; off >>= 1) {
      p0 += __shfl_xor(p0, off);
      p1 += __shfl_xor(p1, off);
    }
    if (e == 0) {
      float b3 = A3_b[0];
      if (l0 < len) logit_s[l0] = p0 + b3;
      if (l1 < len) logit_s[l1] = p1 + b3;
    }
    __syncthreads();
  }

  if (g == 0) {
    float lg = logit_s[e];
    float m = lg;
#pragma unroll
    for (int off = 32; off > 0; off >>= 1) m = fmaxf(m, __shfl_xor(m, off));
    float pe = __expf(lg - m);
    float sm = pe;
#pragma unroll
    for (int off = 32; off > 0; off >>= 1) sm += __shfl_xor(sm, off);
    att_s[e] = pe / sm;
  }
  __syncthreads();

  {
    const int l_lo = 13 * g;
    const int l_hi = (13 * g + 13 < LL) ? 13 * g + 13 : LL;
    float h = 0.f;
    for (int l = l_lo; l < l_hi; ++l) h = fmaf(att_s[l], o_s[l][e], h);
    red_s[g][e] = h;
  }
  __syncthreads();

  if (g == 0) {
    float h = red_s[0][e] + red_s[1][e] + red_s[2][e] + red_s[3][e];
    float acc = Ow_b[e];
#pragma unroll
    for (int k = 0; k < 64; ++k) {
      float hk = __shfl(h, k);
      acc = fmaf(hk, Ow_w[k * EE + e], acc);
    }
#pragma unroll
    for (int k = 0; k < 64; ++k) {
      float pk = __shfl(p, k);
      acc = fmaf(pk, Ow_w[(64 + k) * EE + e], acc);
    }
    out[(size_t)n * EE + e] = fmaxf(acc, 0.f);
  }
}

// ---------------- launcher ----------------
extern "C" void kernel_launch(void* const* d_in, const int* in_sizes, int n_in,
                              void* d_out, int out_size, void* d_ws, size_t ws_size,
                              hipStream_t stream) {
  const float* u2e         = (const float*)d_in[0];
  const float* r2e         = (const float*)d_in[1];
  const float* content_emb = (const float*)d_in[2];
  const float* We_w = (const float*)d_in[3];
  const float* We_b = (const float*)d_in[4];
  const float* W1_w = (const float*)d_in[5];
  const float* W1_b = (const float*)d_in[6];
  const float* W2_w = (const float*)d_in[7];
  const float* W2_b = (const float*)d_in[8];
  const float* A1_w = (const float*)d_in[9];
  const float* A1_b = (const float*)d_in[10];
  const float* A2_w = (const float*)d_in[11];
  const float* A2_b = (const float*)d_in[12];
  const float* A3_w = (const float*)d_in[13];
  const float* A3_b = (const float*)d_in[14];
  const float* Ow_w = (const float*)d_in[15];
  const float* Ow_b = (const float*)d_in[16];
  // d_in[17] = nodes (unused)
  const int* pu_history = (const int*)d_in[18];
  const int* pr_history = (const int*)d_in[19];
  const int* lengths    = (const int*)d_in[20];
  const int* pr_content = (const int*)d_in[21];
  float* out = (float*)d_out;

  // workspace layout (bytes)
  const size_t FR_OFF  = 0;                        // 2560 short8 = 40960 B
  const size_t PO_OFF  = 65536;                    // post f32 [N*64]
  const size_t AB_OFF  = PO_OFF + (size_t)NN * EE * 4;
  const size_t UBF_OFF = AB_OFF + (size_t)NN * EE * 4;   // bf16 u2e+r2e tables
  const size_t NEED    = UBF_OFF + (size_t)(NUE + 384) * 2;  // ~21.3 MB

  if (ws_size < NEED) {
    postenc_kernel<<<NN, 256, 0, stream>>>(
        u2e, r2e, content_emb, We_w, We_b, W1_w, W1_b, W2_w, W2_b,
        A1_w, A1_b, A2_w, A2_b, A3_w, A3_b, Ow_w, Ow_b,
        pu_history, pr_history, lengths, pr_content, out);
    return;
  }

  char* w = (char*)d_ws;
  unsigned short* frag_ws = (unsigned short*)(w + FR_OFF);
  float* post_ws  = (float*)(w + PO_OFF);
  float* abase_ws = (float*)(w + AB_OFF);
  unsigned short* ur_bf = (unsigned short*)(w + UBF_OFF);

  conv_kernel<<<2048, 256, 0, stream>>>(u2e, r2e, ur_bf);
  pack_kernel<<<4, 256, 0, stream>>>(W1_w, W2_w, A1_w, A2_w, frag_ws);
  setup_kernel<<<NN, 64, 0, stream>>>(content_emb, pr_content, We_w, We_b,
                                      A1_w, A1_b, post_ws, abase_ws);
  fused_kernel<<<768, 256, 0, stream>>>(
      ur_bf, W1_b, W2_b, A2_b, A3_w, A3_b, Ow_w, Ow_b,
      pu_history, pr_history, lengths, (const short8*)frag_ws,
      post_ws, abase_ws, out);
}